// Round 4
// baseline (1011.172 us; speedup 1.0000x reference)
//
#include <hip/hip_runtime.h>
#include <stdint.h>

typedef unsigned short u16;
typedef unsigned char  u8;
typedef unsigned int   u32;
typedef __attribute__((ext_vector_type(8))) short  short8;
typedef __attribute__((ext_vector_type(4))) float  floatx4;

#define Bz   16
#define Mm   1024
#define Nn   1024
#define Dd   1024
#define HIDh 512
#define INV_SQRT_D 0.03125f
#define NEGINF (-1.0e9f)
#define BMDc  ((size_t)Bz * Mm * Dd)
#define sMDc  ((long)Mm * Dd)

__device__ __forceinline__ float bf2f(u16 h) {
    union { u32 u; float f; } c; c.u = ((u32)h) << 16; return c.f;
}
__device__ __forceinline__ u16 f2bf(float f) {
    union { float f; u32 u; } c; c.f = f;
    u32 u = c.u;
    return (u16)((u + 0x7FFFu + ((u >> 16) & 1u)) >> 16);
}
// async global->LDS, 16B/lane; lds ptr wave-uniform (HW adds lane*16)
__device__ __forceinline__ void g2lds16(const u16* g, u16* l) {
    __builtin_amdgcn_global_load_lds((const __attribute__((address_space(1))) void*)g,
                                     (__attribute__((address_space(3))) void*)l, 16, 0, 0);
}

__device__ __forceinline__ float waveSum(float v) {
#pragma unroll
    for (int o = 32; o > 0; o >>= 1) v += __shfl_xor(v, o);
    return v;
}
__device__ __forceinline__ float waveMax(float v) {
#pragma unroll
    for (int o = 32; o > 0; o >>= 1) v = fmaxf(v, __shfl_xor(v, o));
    return v;
}

// ===================== 256x256 8-phase GEMM:  C = A * B^T  (bf16 in, fp32 acc) =====================
// (verified round-2; byte-identical)  Schedule: per K-tile t, BK=64, buf cb=t&1; 4 phases.
//   reads retire:  ph0: A-lo + B-lo;  ph1: B-hi;  ph2: A-hi;  ph3: none
//   stages: ph0: B-lo(t+1)->buf^1; ph1: A-lo(t+2)->buf; ph2: B-hi(t+2)->buf; ph3: A-hi(t+2)->buf
//   vmcnt(6) once per tile boundary; LDS 16B-chunk XOR swizzle (both-sides pattern).
template <bool OUT_FP32, bool BIAS, bool TRANSC>
__global__ __launch_bounds__(512, 2) void gemm256(
    const u16* __restrict__ A, const u16* __restrict__ Bm,
    const float* __restrict__ bias, void* __restrict__ Cv,
    int K, int ldc, long sA, long sB, long sC)
{
    __shared__ __align__(16) u16 lds[2][2][256 * 64];   // [buf][A=0/B=1][row*64+col], 128 KiB
    const int tid  = threadIdx.x;
    const int lane = tid & 63;
    const int wv   = tid >> 6;
    const int wr   = wv >> 2;
    const int wc   = wv & 3;
    const int fr   = lane & 15, fq = lane >> 4;

    const int gX = gridDim.x, gY = gridDim.y;
    int bid = blockIdx.x + gX * (blockIdx.y + gY * blockIdx.z);
    const int nwg = gX * gY * gridDim.z;
    int wg = (bid & 7) * (nwg >> 3) + (bid >> 3);
    const int bx = wg % gX; wg /= gX;
    const int by = wg % gY;
    const int bz = wg / gY;

    const long tileM = (long)bx * 256, tileN = (long)by * 256;
    A  += (long)bz * sA;
    Bm += (long)bz * sB;
    const int T = K >> 6;

    floatx4 acc[8][4];
#pragma unroll
    for (int i = 0; i < 8; ++i)
#pragma unroll
        for (int j = 0; j < 4; ++j) acc[i][j] = (floatx4){0.f, 0.f, 0.f, 0.f};

    const int lrow = lane >> 3;
    const int scol = ((lane & 7) ^ lrow) << 3;
    const int sw   = fr & 7;
    const int kc0  = ((fq ^ sw) << 3);
    const int kc1  = (((4 + fq) ^ sw) << 3);

    auto stage = [&](int tt, int side, int hh, int bb) {
#pragma unroll
        for (int i = 0; i < 2; ++i) {
            const int j = i * 8 + wv;
            const int prow = side ? (((j >> 2) << 6) + (hh << 5) + ((j & 3) << 3))
                                  : (((j >> 3) << 7) + (hh << 6) + ((j & 7) << 3));
            const u16* src = side ? Bm : A;
            const long rb  = side ? tileN : tileM;
            g2lds16(src + (size_t)(rb + prow + lrow) * (size_t)K + (size_t)(tt << 6) + scol,
                    &lds[bb][side][prow * 64]);
        }
    };

    short8 Af[4][2], Bf[4][2];
    auto quad = [&](int mb, int nb) {
#pragma unroll
        for (int m = 0; m < 4; ++m)
#pragma unroll
            for (int n = 0; n < 2; ++n) {
                acc[mb + m][nb + n] = __builtin_amdgcn_mfma_f32_16x16x32_bf16(
                    Af[m][0], Bf[nb + n][0], acc[mb + m][nb + n], 0, 0, 0);
                acc[mb + m][nb + n] = __builtin_amdgcn_mfma_f32_16x16x32_bf16(
                    Af[m][1], Bf[nb + n][1], acc[mb + m][nb + n], 0, 0, 0);
            }
    };

    stage(0, 0, 0, 0); stage(0, 1, 0, 0); stage(0, 1, 1, 0); stage(0, 0, 1, 0);
    stage(1, 0, 0, 1); stage(1, 1, 1, 1); stage(1, 0, 1, 1);
    asm volatile("s_waitcnt vmcnt(6)" ::: "memory");
    __builtin_amdgcn_s_barrier();

    for (int t = 0; t < T; ++t) {
        const int cb = t & 1;
        const u16* lA = &lds[cb][0][0];
        const u16* lB = &lds[cb][1][0];

#pragma unroll
        for (int m = 0; m < 4; ++m) {
            const int ro = ((wr << 7) + (m << 4) + fr) * 64;
            Af[m][0] = *(const short8*)&lA[ro + kc0];
            Af[m][1] = *(const short8*)&lA[ro + kc1];
        }
#pragma unroll
        for (int n = 0; n < 2; ++n) {
            const int ro = ((wc << 6) + (n << 4) + fr) * 64;
            Bf[n][0] = *(const short8*)&lB[ro + kc0];
            Bf[n][1] = *(const short8*)&lB[ro + kc1];
        }
        if (t + 1 < T) stage(t + 1, 1, 0, cb ^ 1);
        asm volatile("" ::: "memory");
        __builtin_amdgcn_s_barrier();
        asm volatile("s_waitcnt lgkmcnt(0)" ::: "memory");
        __builtin_amdgcn_sched_barrier(0);
        __builtin_amdgcn_s_setprio(1);
        quad(0, 0);
        __builtin_amdgcn_s_setprio(0);
        asm volatile("" ::: "memory");
        __builtin_amdgcn_s_barrier();

#pragma unroll
        for (int n = 2; n < 4; ++n) {
            const int ro = ((wc << 6) + (n << 4) + fr) * 64;
            Bf[n][0] = *(const short8*)&lB[ro + kc0];
            Bf[n][1] = *(const short8*)&lB[ro + kc1];
        }
        if (t + 2 < T) stage(t + 2, 0, 0, cb);
        asm volatile("" ::: "memory");
        __builtin_amdgcn_s_barrier();
        asm volatile("s_waitcnt lgkmcnt(0)" ::: "memory");
        __builtin_amdgcn_sched_barrier(0);
        __builtin_amdgcn_s_setprio(1);
        quad(0, 2);
        __builtin_amdgcn_s_setprio(0);
        asm volatile("" ::: "memory");
        __builtin_amdgcn_s_barrier();

#pragma unroll
        for (int m = 0; m < 4; ++m) {
            const int ro = ((wr << 7) + ((m + 4) << 4) + fr) * 64;
            Af[m][0] = *(const short8*)&lA[ro + kc0];
            Af[m][1] = *(const short8*)&lA[ro + kc1];
        }
        if (t + 2 < T) stage(t + 2, 1, 1, cb);
        asm volatile("" ::: "memory");
        __builtin_amdgcn_s_barrier();
        asm volatile("s_waitcnt lgkmcnt(0)" ::: "memory");
        __builtin_amdgcn_sched_barrier(0);
        __builtin_amdgcn_s_setprio(1);
        quad(4, 2);
        __builtin_amdgcn_s_setprio(0);
        asm volatile("" ::: "memory");
        __builtin_amdgcn_s_barrier();

        if (t + 2 < T) stage(t + 2, 0, 1, cb);
        asm volatile("" ::: "memory");
        __builtin_amdgcn_s_barrier();
        __builtin_amdgcn_s_setprio(1);
        quad(4, 0);
        __builtin_amdgcn_s_setprio(0);
        if (t + 1 < T) {
            if (t + 2 < T) asm volatile("s_waitcnt vmcnt(6)" ::: "memory");
            else           asm volatile("s_waitcnt vmcnt(0)" ::: "memory");
        }
        asm volatile("" ::: "memory");
        __builtin_amdgcn_s_barrier();
    }

#pragma unroll
    for (int j = 0; j < 4; ++j) {
        const long col = tileN + (wc << 6) + (j << 4) + fr;
        float bv = 0.f;
        if constexpr (BIAS) bv = bias[col];
#pragma unroll
        for (int i = 0; i < 8; ++i) {
            const long row0 = tileM + (wr << 7) + (i << 4) + (fq << 2);
#pragma unroll
            for (int r = 0; r < 4; ++r) {
                const float v = acc[i][j][r] + bv;
                const long row = row0 + r;
                if constexpr (OUT_FP32) {
                    ((float*)Cv + (long)bz * sC)[row * ldc + col] = v;
                } else if constexpr (TRANSC) {
                    const long b = row >> 10, mloc = row & 1023;
                    ((u16*)Cv)[b * sMDc + col * Mm + mloc] = f2bf(v);
                } else {
                    ((u16*)Cv + (long)bz * sC)[row * ldc + col] = f2bf(v);
                }
            }
        }
    }
}

// ===================== fused 3-projection GEMM: [Q|K|V] = A(16384x1024) * Wcat(3072x1024)^T =====================
// Same engine as gemm256 (literal copy of the verified pipeline); epilogue routes by N-segment:
//   cols [0,1024) -> Pq row-major; [1024,2048) -> Pk row-major; [2048,3072) -> Pv TRANSPOSED per batch.
__global__ __launch_bounds__(512, 2) void gemm_proj3(
    const u16* __restrict__ A, const u16* __restrict__ Bm,
    const float* __restrict__ bcat,
    u16* __restrict__ Pq, u16* __restrict__ Pk, u16* __restrict__ Pv, int K)
{
    __shared__ __align__(16) u16 lds[2][2][256 * 64];
    const int tid  = threadIdx.x;
    const int lane = tid & 63;
    const int wv   = tid >> 6;
    const int wr   = wv >> 2;
    const int wc   = wv & 3;
    const int fr   = lane & 15, fq = lane >> 4;

    const int gX = gridDim.x, gY = gridDim.y;
    int bid = blockIdx.x + gX * blockIdx.y;
    const int nwg = gX * gY;
    int wg = (bid & 7) * (nwg >> 3) + (bid >> 3);
    const int bx = wg % gX;
    const int by = wg / gX;

    const long tileM = (long)bx * 256, tileN = (long)by * 256;
    const int T = K >> 6;

    floatx4 acc[8][4];
#pragma unroll
    for (int i = 0; i < 8; ++i)
#pragma unroll
        for (int j = 0; j < 4; ++j) acc[i][j] = (floatx4){0.f, 0.f, 0.f, 0.f};

    const int lrow = lane >> 3;
    const int scol = ((lane & 7) ^ lrow) << 3;
    const int sw   = fr & 7;
    const int kc0  = ((fq ^ sw) << 3);
    const int kc1  = (((4 + fq) ^ sw) << 3);

    auto stage = [&](int tt, int side, int hh, int bb) {
#pragma unroll
        for (int i = 0; i < 2; ++i) {
            const int j = i * 8 + wv;
            const int prow = side ? (((j >> 2) << 6) + (hh << 5) + ((j & 3) << 3))
                                  : (((j >> 3) << 7) + (hh << 6) + ((j & 7) << 3));
            const u16* src = side ? Bm : A;
            const long rb  = side ? tileN : tileM;
            g2lds16(src + (size_t)(rb + prow + lrow) * (size_t)K + (size_t)(tt << 6) + scol,
                    &lds[bb][side][prow * 64]);
        }
    };

    short8 Af[4][2], Bf[4][2];
    auto quad = [&](int mb, int nb) {
#pragma unroll
        for (int m = 0; m < 4; ++m)
#pragma unroll
            for (int n = 0; n < 2; ++n) {
                acc[mb + m][nb + n] = __builtin_amdgcn_mfma_f32_16x16x32_bf16(
                    Af[m][0], Bf[nb + n][0], acc[mb + m][nb + n], 0, 0, 0);
                acc[mb + m][nb + n] = __builtin_amdgcn_mfma_f32_16x16x32_bf16(
                    Af[m][1], Bf[nb + n][1], acc[mb + m][nb + n], 0, 0, 0);
            }
    };

    stage(0, 0, 0, 0); stage(0, 1, 0, 0); stage(0, 1, 1, 0); stage(0, 0, 1, 0);
    stage(1, 0, 0, 1); stage(1, 1, 1, 1); stage(1, 0, 1, 1);
    asm volatile("s_waitcnt vmcnt(6)" ::: "memory");
    __builtin_amdgcn_s_barrier();

    for (int t = 0; t < T; ++t) {
        const int cb = t & 1;
        const u16* lA = &lds[cb][0][0];
        const u16* lB = &lds[cb][1][0];

#pragma unroll
        for (int m = 0; m < 4; ++m) {
            const int ro = ((wr << 7) + (m << 4) + fr) * 64;
            Af[m][0] = *(const short8*)&lA[ro + kc0];
            Af[m][1] = *(const short8*)&lA[ro + kc1];
        }
#pragma unroll
        for (int n = 0; n < 2; ++n) {
            const int ro = ((wc << 6) + (n << 4) + fr) * 64;
            Bf[n][0] = *(const short8*)&lB[ro + kc0];
            Bf[n][1] = *(const short8*)&lB[ro + kc1];
        }
        if (t + 1 < T) stage(t + 1, 1, 0, cb ^ 1);
        asm volatile("" ::: "memory");
        __builtin_amdgcn_s_barrier();
        asm volatile("s_waitcnt lgkmcnt(0)" ::: "memory");
        __builtin_amdgcn_sched_barrier(0);
        __builtin_amdgcn_s_setprio(1);
        quad(0, 0);
        __builtin_amdgcn_s_setprio(0);
        asm volatile("" ::: "memory");
        __builtin_amdgcn_s_barrier();

#pragma unroll
        for (int n = 2; n < 4; ++n) {
            const int ro = ((wc << 6) + (n << 4) + fr) * 64;
            Bf[n][0] = *(const short8*)&lB[ro + kc0];
            Bf[n][1] = *(const short8*)&lB[ro + kc1];
        }
        if (t + 2 < T) stage(t + 2, 0, 0, cb);
        asm volatile("" ::: "memory");
        __builtin_amdgcn_s_barrier();
        asm volatile("s_waitcnt lgkmcnt(0)" ::: "memory");
        __builtin_amdgcn_sched_barrier(0);
        __builtin_amdgcn_s_setprio(1);
        quad(0, 2);
        __builtin_amdgcn_s_setprio(0);
        asm volatile("" ::: "memory");
        __builtin_amdgcn_s_barrier();

#pragma unroll
        for (int m = 0; m < 4; ++m) {
            const int ro = ((wr << 7) + ((m + 4) << 4) + fr) * 64;
            Af[m][0] = *(const short8*)&lA[ro + kc0];
            Af[m][1] = *(const short8*)&lA[ro + kc1];
        }
        if (t + 2 < T) stage(t + 2, 1, 1, cb);
        asm volatile("" ::: "memory");
        __builtin_amdgcn_s_barrier();
        asm volatile("s_waitcnt lgkmcnt(0)" ::: "memory");
        __builtin_amdgcn_sched_barrier(0);
        __builtin_amdgcn_s_setprio(1);
        quad(4, 2);
        __builtin_amdgcn_s_setprio(0);
        asm volatile("" ::: "memory");
        __builtin_amdgcn_s_barrier();

        if (t + 2 < T) stage(t + 2, 0, 1, cb);
        asm volatile("" ::: "memory");
        __builtin_amdgcn_s_barrier();
        __builtin_amdgcn_s_setprio(1);
        quad(4, 0);
        __builtin_amdgcn_s_setprio(0);
        if (t + 1 < T) {
            if (t + 2 < T) asm volatile("s_waitcnt vmcnt(6)" ::: "memory");
            else           asm volatile("s_waitcnt vmcnt(0)" ::: "memory");
        }
        asm volatile("" ::: "memory");
        __builtin_amdgcn_s_barrier();
    }

#pragma unroll
    for (int j = 0; j < 4; ++j) {
        const long colL = tileN + (wc << 6) + (j << 4) + fr;
        const int oid = (int)(colL >> 10);          // uniform per block (tileN multiple of 256)
        const long col = colL & 1023;
        const float bv = bcat[colL];
#pragma unroll
        for (int i = 0; i < 8; ++i) {
            const long row0 = tileM + (wr << 7) + (i << 4) + (fq << 2);
#pragma unroll
            for (int r = 0; r < 4; ++r) {
                const float v = acc[i][j][r] + bv;
                const long row = row0 + r;
                if (oid == 0)      Pq[row * Dd + col] = f2bf(v);
                else if (oid == 1) Pk[row * Dd + col] = f2bf(v);
                else { const long b = row >> 10, mloc = row & 1023;
                       Pv[b * sMDc + col * Mm + mloc] = f2bf(v); }
            }
        }
    }
}

// ---------------- fused fp32->bf16 conversion + column-mean pooling ----------------
// grid (16 row-chunks, 16 batches, 2 sources); each block: 64 rows x 1024 cols.
__global__ __launch_bounds__(256) void conv_pool(
    const float* __restrict__ oV, const float* __restrict__ oT,
    u16* __restrict__ oVb, u16* __restrict__ oTb,
    float* __restrict__ vpool, float* __restrict__ tpool)
{
    const int b = blockIdx.y, srci = blockIdx.z;
    const float* src = (srci ? oT : oV) + (size_t)b * Mm * Dd;
    u16* dst = (srci ? oTb : oVb) + (size_t)b * Mm * Dd;
    const int c4 = threadIdx.x * 4;
    const int r0 = blockIdx.x * 64;
    float4 s = {0.f, 0.f, 0.f, 0.f};
    for (int r = r0; r < r0 + 64; ++r) {
        const float4 v = *(const float4*)&src[(size_t)r * Dd + c4];
        s.x += v.x; s.y += v.y; s.z += v.z; s.w += v.w;
        ushort4 o;
        o.x = f2bf(v.x); o.y = f2bf(v.y); o.z = f2bf(v.z); o.w = f2bf(v.w);
        *(ushort4*)&dst[(size_t)r * Dd + c4] = o;
    }
    float* pool = (srci ? tpool : vpool) + (size_t)b * Dd + c4;
    atomicAdd(pool + 0, s.x * (1.0f / Mm));
    atomicAdd(pool + 1, s.y * (1.0f / Mm));
    atomicAdd(pool + 2, s.z * (1.0f / Mm));
    atomicAdd(pool + 3, s.w * (1.0f / Mm));
}

// ---------------- 6x weight fp32 -> bf16 (one launch) ----------------
__global__ __launch_bounds__(256) void wconv6(
    const float* __restrict__ w0, const float* __restrict__ w1, const float* __restrict__ w2,
    const float* __restrict__ w3, const float* __restrict__ w4, const float* __restrict__ w5,
    u16* __restrict__ dst)
{
    const float* src;
    switch (blockIdx.y) {
        case 0: src = w0; break; case 1: src = w1; break; case 2: src = w2; break;
        case 3: src = w3; break; case 4: src = w4; break; default: src = w5; break;
    }
    const size_t i = (size_t)blockIdx.x * 256 + threadIdx.x;
    const float4 a = ((const float4*)src)[2 * i];
    const float4 b = ((const float4*)src)[2 * i + 1];
    short8 o;
    o[0]=(short)f2bf(a.x); o[1]=(short)f2bf(a.y); o[2]=(short)f2bf(a.z); o[3]=(short)f2bf(a.w);
    o[4]=(short)f2bf(b.x); o[5]=(short)f2bf(b.y); o[6]=(short)f2bf(b.z); o[7]=(short)f2bf(b.w);
    *(short8*)(dst + (((size_t)blockIdx.y) << 20) + 8 * i) = o;
}

// ---------------- concat 6 bias vectors -> bcat[6144] ----------------
__global__ __launch_bounds__(256) void bcat_kernel(
    const float* __restrict__ b0, const float* __restrict__ b1, const float* __restrict__ b2,
    const float* __restrict__ b3, const float* __restrict__ b4, const float* __restrict__ b5,
    float* __restrict__ out)
{
    const int i = blockIdx.x * 256 + threadIdx.x;   // 6144 total
    const int seg = i >> 10;
    const float* s;
    switch (seg) {
        case 0: s = b0; break; case 1: s = b1; break; case 2: s = b2; break;
        case 3: s = b3; break; case 4: s = b4; break; default: s = b5; break;
    }
    out[i] = s[i & 1023];
}

// ---------------- FFN ----------------
__global__ __launch_bounds__(256) void ffn1_kernel(
    const float* __restrict__ vpool, const float* __restrict__ tpool,
    const float* __restrict__ f1w, const float* __restrict__ f1b,
    float* __restrict__ hbuf)
{
    const int j = blockIdx.x, b = blockIdx.y;
    const int t = threadIdx.x, wv = t >> 6, lane = t & 63;
    __shared__ float red[4];
    const float* w = f1w + (size_t)j * (2 * Dd);
    float a = 0.f;
    for (int k = t; k < Dd; k += 256) a += vpool[b * Dd + k] * w[k];
    for (int k = t; k < Dd; k += 256) a += tpool[b * Dd + k] * w[Dd + k];
    a = waveSum(a);
    if (lane == 0) red[wv] = a;
    __syncthreads();
    if (t == 0) hbuf[b * HIDh + j] = fmaxf(red[0] + red[1] + red[2] + red[3] + f1b[j], 0.0f);
}

__global__ __launch_bounds__(256) void ffn2_kernel(
    const float* __restrict__ hbuf, const float* __restrict__ f2w,
    const float* __restrict__ f2b, float* __restrict__ lbuf)
{
    const int b = blockIdx.x;
    const int t = threadIdx.x, wv = t >> 6, lane = t & 63;
    __shared__ float red[4];
    float p = 0.f;
    for (int j = t; j < HIDh; j += 256) p += hbuf[b * HIDh + j] * f2w[j];
    p = waveSum(p);
    if (lane == 0) red[wv] = p;
    __syncthreads();
    if (t == 0) {
        const float z = red[0] + red[1] + red[2] + red[3] + f2b[0];
        lbuf[b] = 1.0f / (1.0f + expf(-z));
    }
}

// ---------------- sim softmax -> fp32 mask (d_out) ----------------
__global__ __launch_bounds__(256) void sim_softmax_mask(
    const u16* __restrict__ scores, const float* __restrict__ lbuf, float* __restrict__ maskF)
{
    const int row = blockIdx.x, b = blockIdx.y;
    const int t = threadIdx.x, wv = t >> 6, lane = t & 63;
    __shared__ float red[8];
    const size_t off = ((size_t)b * Mm + row) * Nn;
    const uint2 sv = *(const uint2*)(scores + off + 4 * t);
    const float x0 = bf2f((u16)(sv.x & 0xFFFFu)) * INV_SQRT_D;
    const float x1 = bf2f((u16)(sv.x >> 16))     * INV_SQRT_D;
    const float x2 = bf2f((u16)(sv.y & 0xFFFFu)) * INV_SQRT_D;
    const float x3 = bf2f((u16)(sv.y >> 16))     * INV_SQRT_D;
    float mx = waveMax(fmaxf(fmaxf(x0, x1), fmaxf(x2, x3)));
    if (lane == 0) red[wv] = mx;
    __syncthreads();
    mx = fmaxf(fmaxf(red[0], red[1]), fmaxf(red[2], red[3]));
    const float e0 = expf(x0 - mx), e1 = expf(x1 - mx), e2 = expf(x2 - mx), e3 = expf(x3 - mx);
    float s = waveSum(e0 + e1 + e2 + e3);
    if (lane == 0) red[4 + wv] = s;
    __syncthreads();
    const float inv = 1.0f / fmaxf(red[4] + red[5] + red[6] + red[7], 1e-30f);
    const float l = lbuf[b];
    float4 mk;
    mk.x = (e0 * inv >= l) ? 1.0f : 0.0f;
    mk.y = (e1 * inv >= l) ? 1.0f : 0.0f;
    mk.z = (e2 * inv >= l) ? 1.0f : 0.0f;
    mk.w = (e3 * inv >= l) ? 1.0f : 0.0f;
    *(float4*)(maskF + off + 4 * t) = mk;
}

// ---------------- mask transpose: fp32 mask[b][m][n] -> u8 maskT[b][n][m] ----------------
__global__ __launch_bounds__(256) void transpose_mask(
    const float* __restrict__ maskF, u8* __restrict__ maskT)
{
    __shared__ u8 tile[64][68];
    const int m0 = blockIdx.x * 64, n0 = blockIdx.y * 64, b = blockIdx.z;
    const int t = threadIdx.x;
    const int r = t >> 2, c = (t & 3) * 16;
    const float* src = maskF + ((size_t)b * Mm + (m0 + r)) * Nn + n0 + c;
    float4 f0 = ((const float4*)src)[0];
    float4 f1 = ((const float4*)src)[1];
    float4 f2 = ((const float4*)src)[2];
    float4 f3 = ((const float4*)src)[3];
    u8* dst = &tile[r][c];
    dst[0]=f0.x!=0.f; dst[1]=f0.y!=0.f; dst[2]=f0.z!=0.f; dst[3]=f0.w!=0.f;
    dst[4]=f1.x!=0.f; dst[5]=f1.y!=0.f; dst[6]=f1.z!=0.f; dst[7]=f1.w!=0.f;
    dst[8]=f2.x!=0.f; dst[9]=f2.y!=0.f; dst[10]=f2.z!=0.f; dst[11]=f2.w!=0.f;
    dst[12]=f3.x!=0.f; dst[13]=f3.y!=0.f; dst[14]=f3.z!=0.f; dst[15]=f3.w!=0.f;
    __syncthreads();
    union { u8 b[16]; uint4 v; } pk;
#pragma unroll
    for (int k = 0; k < 16; ++k) pk.b[k] = tile[c + k][r];
    *(uint4*)(maskT + ((size_t)b * Nn + (n0 + r)) * Mm + m0 + c) = pk.v;
}

// ---------------- masked softmax over bf16 scores, IN-PLACE -> bf16 attn ----------------
template <bool TRANSP>
__global__ __launch_bounds__(256) void masked_softmax(
    u16* __restrict__ scores, const float* __restrict__ maskF, const u8* __restrict__ maskT)
{
    const int row = blockIdx.x, b = blockIdx.y;
    const int t = threadIdx.x, wv = t >> 6, lane = t & 63;
    __shared__ float red[8];
    const size_t off = ((size_t)b * Mm + row) * Nn;
    const uint2 sv = *(const uint2*)(scores + off + 4 * t);
    float x0 = bf2f((u16)(sv.x & 0xFFFFu)) * INV_SQRT_D;
    float x1 = bf2f((u16)(sv.x >> 16))     * INV_SQRT_D;
    float x2 = bf2f((u16)(sv.y & 0xFFFFu)) * INV_SQRT_D;
    float x3 = bf2f((u16)(sv.y >> 16))     * INV_SQRT_D;
    if (TRANSP) {
        const u32 mk = *(const u32*)(maskT + off + 4 * t);
        if (!(mk & 0x000000FFu)) x0 = NEGINF;
        if (!(mk & 0x0000FF00u)) x1 = NEGINF;
        if (!(mk & 0x00FF0000u)) x2 = NEGINF;
        if (!(mk & 0xFF000000u)) x3 = NEGINF;
    } else {
        const float4 mk = *(const float4*)(maskF + off + 4 * t);
        if (mk.x == 0.f) x0 = NEGINF;
        if (mk.y == 0.f) x1 = NEGINF;
        if (mk.z == 0.f) x2 = NEGINF;
        if (mk.w == 0.f) x3 = NEGINF;
    }
    float mx = waveMax(fmaxf(fmaxf(x0, x1), fmaxf(x2, x3)));
    if (lane == 0) red[wv] = mx;
    __syncthreads();
    mx = fmaxf(fmaxf(red[0], red[1]), fmaxf(red[2], red[3]));
    const float e0 = expf(x0 - mx), e1 = expf(x1 - mx), e2 = expf(x2 - mx), e3 = expf(x3 - mx);
    float s = waveSum(e0 + e1 + e2 + e3);
    if (lane == 0) red[4 + wv] = s;
    __syncthreads();
    const float inv = 1.0f / fmaxf(red[4] + red[5] + red[6] + red[7], 1e-30f);
    uint2 pk;
    pk.x = (u32)f2bf(e0 * inv) | ((u32)f2bf(e1 * inv) << 16);
    pk.y = (u32)f2bf(e2 * inv) | ((u32)f2bf(e3 * inv) << 16);
    *(uint2*)(scores + off + 4 * t) = pk;
}

extern "C" void kernel_launch(void* const* d_in, const int* in_sizes, int n_in,
                              void* d_out, int out_size, void* d_ws, size_t ws_size,
                              hipStream_t stream)
{
    (void)in_sizes; (void)n_in; (void)out_size; (void)ws_size;
    const float* oV     = (const float*)d_in[0];
    const float* oT     = (const float*)d_in[1];
    const float* Wq_v_w = (const float*)d_in[2];
    const float* Wq_v_b = (const float*)d_in[3];
    const float* Wk_t_w = (const float*)d_in[4];
    const float* Wk_t_b = (const float*)d_in[5];
    const float* Wv_t_w = (const float*)d_in[6];
    const float* Wv_t_b = (const float*)d_in[7];
    const float* Wq_t_w = (const float*)d_in[8];
    const float* Wq_t_b = (const float*)d_in[9];
    const float* Wk_v_w = (const float*)d_in[10];
    const float* Wk_v_b = (const float*)d_in[11];
    const float* Wv_v_w = (const float*)d_in[12];
    const float* Wv_v_b = (const float*)d_in[13];
    const float* f1w    = (const float*)d_in[14];
    const float* f1b    = (const float*)d_in[15];
    const float* f2w    = (const float*)d_in[16];
    const float* f2b    = (const float*)d_in[17];

    float* out_vt = (float*)d_out;
    float* out_tv = out_vt + BMDc;
    float* maskF  = out_vt + 2 * BMDc;

    // workspace layout (~320 MB of 768 MB)
    u16* S0a = (u16*)d_ws;                       // Qv                  32 MB
    u16* S1a = S0a + BMDc;                       // Kt                  32 MB
    u16* S2a = S1a + BMDc;                       // Vt^T                32 MB
    u16* S0b = S2a + BMDc;                       // Qt                  32 MB
    u16* S1b = S0b + BMDc;                       // Kv                  32 MB
    u16* S2b = S1b + BMDc;                       // Vv^T                32 MB
    u16* S3  = S2b + BMDc;                       // scores/attn         32 MB
    u16* oVb = S3 + BMDc;                        // bf16 oV             32 MB
    u16* oTb = oVb + BMDc;                       // bf16 oT             32 MB
    u16* Wc  = oTb + BMDc;                       // 6x bf16 weights     12 MB
    u8*  maskT = (u8*)(Wc + 6 * (1 << 20));      // transposed u8 mask  16 MB
    float* bcat  = (float*)(maskT + BMDc);       // 6144 floats
    float* vpool = bcat + 6144;
    float* tpool = vpool + Bz * Dd;
    float* hbuf  = tpool + Bz * Dd;
    float* lbuf  = hbuf + Bz * HIDh;

    const dim3 blk(256), blk512(512);
    const dim3 gBat(Mm / 256, Nn / 256, Bz);      // (4,4,16) = 256 wg
    const dim3 gFproj(Bz * Mm / 256, 3 * Dd / 256, 1); // (64,12) = 768 wg
    const dim3 gRow(Mm, Bz);
    const dim3 gTrp(Mm / 64, Nn / 64, Bz);
    const long sMD = sMDc, sMN = (long)Mm * Nn;

    // 0: weights + biases to bf16/concat (independent of inputs)
    wconv6<<<dim3(512, 6), blk, 0, stream>>>(Wq_v_w, Wk_v_w, Wv_v_w, Wq_t_w, Wk_t_w, Wv_t_w, Wc);
    bcat_kernel<<<dim3(24), blk, 0, stream>>>(Wq_v_b, Wk_v_b, Wv_v_b, Wq_t_b, Wk_t_b, Wv_t_b, bcat);

    // 1: fused convert + pool
    hipMemsetAsync(vpool, 0, 2 * Bz * Dd * sizeof(float), stream);
    conv_pool<<<dim3(16, Bz, 2), blk, 0, stream>>>(oV, oT, oVb, oTb, vpool, tpool);
    ffn1_kernel<<<dim3(HIDh, Bz), blk, 0, stream>>>(vpool, tpool, f1w, f1b, hbuf);
    ffn2_kernel<<<dim3(Bz), blk, 0, stream>>>(hbuf, f2w, f2b, lbuf);

    // 2: sim scores -> mask (fp32 out) -> transposed u8 mask
    gemm256<false,false,false><<<gBat, blk512, 0, stream>>>(oVb, oTb, nullptr, S3, Dd, Nn, sMD, sMD, sMN);
    sim_softmax_mask<<<gRow, blk, 0, stream>>>(S3, lbuf, maskF);
    transpose_mask<<<gTrp, blk, 0, stream>>>(maskF, maskT);

    // 3: fused projections.  A=oVb -> {Qv->S0a, Kv->S1b, Vv^T->S2b};  A=oTb -> {Qt->S0b, Kt->S1a, Vt^T->S2a}
    gemm_proj3<<<gFproj, blk512, 0, stream>>>(oVb, Wc,                bcat,        S0a, S1b, S2b, Dd);
    gemm_proj3<<<gFproj, blk512, 0, stream>>>(oTb, Wc + 3 * (1 << 20), bcat + 3072, S0b, S1a, S2a, Dd);

    // 4: V->T attention
    gemm256<false,false,false><<<gBat, blk512, 0, stream>>>(S0a, S1a, nullptr, S3, Dd, Nn, sMD, sMD, sMN);
    masked_softmax<false><<<gRow, blk, 0, stream>>>(S3, maskF, maskT);
    gemm256<true ,false,false><<<gBat, blk512, 0, stream>>>(S3, S2a, nullptr, out_vt, Nn, Dd, sMN, sMD, sMD);

    // 5: T->V attention
    gemm256<false,false,false><<<gBat, blk512, 0, stream>>>(S0b, S1b, nullptr, S3, Dd, Nn, sMD, sMD, sMN);
    masked_softmax<true><<<gRow, blk, 0, stream>>>(S3, maskF, maskT);
    gemm256<true ,false,false><<<gBat, blk512, 0, stream>>>(S3, S2b, nullptr, out_tv, Nn, Dd, sMN, sMD, sMD);
}

// Round 5
// 826.677 us; speedup vs baseline: 1.2232x; 1.2232x over previous
//
#include <hip/hip_runtime.h>
#include <stdint.h>

typedef unsigned short u16;
typedef unsigned char  u8;
typedef unsigned int   u32;
typedef unsigned long long u64;
typedef __attribute__((ext_vector_type(8))) short  short8;
typedef __attribute__((ext_vector_type(4))) float  floatx4;

#define Bz   16
#define Mm   1024
#define Nn   1024
#define Dd   1024
#define HIDh 512
#define INV_SQRT_D 0.03125f
#define NEGINF (-1.0e9f)
#define BMDc  ((size_t)Bz * Mm * Dd)
#define sMDc  ((long)Mm * Dd)

__device__ __forceinline__ float bf2f(u16 h) {
    union { u32 u; float f; } c; c.u = ((u32)h) << 16; return c.f;
}
__device__ __forceinline__ u16 f2bf(float f) {
    union { float f; u32 u; } c; c.f = f;
    u32 u = c.u;
    return (u16)((u + 0x7FFFu + ((u >> 16) & 1u)) >> 16);
}
// async global->LDS, 16B/lane; lds ptr wave-uniform (HW adds lane*16)
__device__ __forceinline__ void g2lds16(const u16* g, u16* l) {
    __builtin_amdgcn_global_load_lds((const __attribute__((address_space(1))) void*)g,
                                     (__attribute__((address_space(3))) void*)l, 16, 0, 0);
}

__device__ __forceinline__ float waveSum(float v) {
#pragma unroll
    for (int o = 32; o > 0; o >>= 1) v += __shfl_xor(v, o);
    return v;
}
__device__ __forceinline__ float waveMax(float v) {
#pragma unroll
    for (int o = 32; o > 0; o >>= 1) v = fmaxf(v, __shfl_xor(v, o));
    return v;
}

// ===================== 256x256 8-phase GEMM:  C = A * B^T  (bf16 in, fp32 acc) =====================
// K-loop verified rounds 2/4 (SQ_LDS_BANK_CONFLICT=0). NEW: LDS-bounce epilogue -> full-line stores
// (round-4 counters: 2-B scatter epilogue caused WRITE 2x and ~96MB of write-allocate RMW FETCH).
template <bool OUT_FP32>
__global__ __launch_bounds__(512, 2) void gemm256(
    const u16* __restrict__ A, const u16* __restrict__ Bm,
    void* __restrict__ Cv, int K, int ldc, long sA, long sB, long sC)
{
    __shared__ __align__(16) u16 lds[2][2][256 * 64];   // [buf][A=0/B=1][row*64+col], 128 KiB
    const int tid  = threadIdx.x;
    const int lane = tid & 63;
    const int wv   = tid >> 6;
    const int wr   = wv >> 2;
    const int wc   = wv & 3;
    const int fr   = lane & 15, fq = lane >> 4;

    const int gX = gridDim.x, gY = gridDim.y;
    int bid = blockIdx.x + gX * (blockIdx.y + gY * blockIdx.z);
    const int nwg = gX * gY * gridDim.z;
    int wg = (bid & 7) * (nwg >> 3) + (bid >> 3);
    const int bx = wg % gX; wg /= gX;
    const int by = wg % gY;
    const int bz = wg / gY;

    const long tileM = (long)bx * 256, tileN = (long)by * 256;
    A  += (long)bz * sA;
    Bm += (long)bz * sB;
    const int T = K >> 6;

    floatx4 acc[8][4];
#pragma unroll
    for (int i = 0; i < 8; ++i)
#pragma unroll
        for (int j = 0; j < 4; ++j) acc[i][j] = (floatx4){0.f, 0.f, 0.f, 0.f};

    const int lrow = lane >> 3;
    const int scol = ((lane & 7) ^ lrow) << 3;
    const int sw   = fr & 7;
    const int kc0  = ((fq ^ sw) << 3);
    const int kc1  = (((4 + fq) ^ sw) << 3);

    auto stage = [&](int tt, int side, int hh, int bb) {
#pragma unroll
        for (int i = 0; i < 2; ++i) {
            const int j = i * 8 + wv;
            const int prow = side ? (((j >> 2) << 6) + (hh << 5) + ((j & 3) << 3))
                                  : (((j >> 3) << 7) + (hh << 6) + ((j & 7) << 3));
            const u16* src = side ? Bm : A;
            const long rb  = side ? tileN : tileM;
            g2lds16(src + (size_t)(rb + prow + lrow) * (size_t)K + (size_t)(tt << 6) + scol,
                    &lds[bb][side][prow * 64]);
        }
    };

    short8 Af[4][2], Bf[4][2];
    auto quad = [&](int mb, int nb) {
#pragma unroll
        for (int m = 0; m < 4; ++m)
#pragma unroll
            for (int n = 0; n < 2; ++n) {
                acc[mb + m][nb + n] = __builtin_amdgcn_mfma_f32_16x16x32_bf16(
                    Af[m][0], Bf[nb + n][0], acc[mb + m][nb + n], 0, 0, 0);
                acc[mb + m][nb + n] = __builtin_amdgcn_mfma_f32_16x16x32_bf16(
                    Af[m][1], Bf[nb + n][1], acc[mb + m][nb + n], 0, 0, 0);
            }
    };

    stage(0, 0, 0, 0); stage(0, 1, 0, 0); stage(0, 1, 1, 0); stage(0, 0, 1, 0);
    stage(1, 0, 0, 1); stage(1, 1, 1, 1); stage(1, 0, 1, 1);
    asm volatile("s_waitcnt vmcnt(6)" ::: "memory");
    __builtin_amdgcn_s_barrier();

    for (int t = 0; t < T; ++t) {
        const int cb = t & 1;
        const u16* lA = &lds[cb][0][0];
        const u16* lB = &lds[cb][1][0];

#pragma unroll
        for (int m = 0; m < 4; ++m) {
            const int ro = ((wr << 7) + (m << 4) + fr) * 64;
            Af[m][0] = *(const short8*)&lA[ro + kc0];
            Af[m][1] = *(const short8*)&lA[ro + kc1];
        }
#pragma unroll
        for (int n = 0; n < 2; ++n) {
            const int ro = ((wc << 6) + (n << 4) + fr) * 64;
            Bf[n][0] = *(const short8*)&lB[ro + kc0];
            Bf[n][1] = *(const short8*)&lB[ro + kc1];
        }
        if (t + 1 < T) stage(t + 1, 1, 0, cb ^ 1);
        asm volatile("" ::: "memory");
        __builtin_amdgcn_s_barrier();
        asm volatile("s_waitcnt lgkmcnt(0)" ::: "memory");
        __builtin_amdgcn_sched_barrier(0);
        __builtin_amdgcn_s_setprio(1);
        quad(0, 0);
        __builtin_amdgcn_s_setprio(0);
        asm volatile("" ::: "memory");
        __builtin_amdgcn_s_barrier();

#pragma unroll
        for (int n = 2; n < 4; ++n) {
            const int ro = ((wc << 6) + (n << 4) + fr) * 64;
            Bf[n][0] = *(const short8*)&lB[ro + kc0];
            Bf[n][1] = *(const short8*)&lB[ro + kc1];
        }
        if (t + 2 < T) stage(t + 2, 0, 0, cb);
        asm volatile("" ::: "memory");
        __builtin_amdgcn_s_barrier();
        asm volatile("s_waitcnt lgkmcnt(0)" ::: "memory");
        __builtin_amdgcn_sched_barrier(0);
        __builtin_amdgcn_s_setprio(1);
        quad(0, 2);
        __builtin_amdgcn_s_setprio(0);
        asm volatile("" ::: "memory");
        __builtin_amdgcn_s_barrier();

#pragma unroll
        for (int m = 0; m < 4; ++m) {
            const int ro = ((wr << 7) + ((m + 4) << 4) + fr) * 64;
            Af[m][0] = *(const short8*)&lA[ro + kc0];
            Af[m][1] = *(const short8*)&lA[ro + kc1];
        }
        if (t + 2 < T) stage(t + 2, 1, 1, cb);
        asm volatile("" ::: "memory");
        __builtin_amdgcn_s_barrier();
        asm volatile("s_waitcnt lgkmcnt(0)" ::: "memory");
        __builtin_amdgcn_sched_barrier(0);
        __builtin_amdgcn_s_setprio(1);
        quad(4, 2);
        __builtin_amdgcn_s_setprio(0);
        asm volatile("" ::: "memory");
        __builtin_amdgcn_s_barrier();

        if (t + 2 < T) stage(t + 2, 0, 1, cb);
        asm volatile("" ::: "memory");
        __builtin_amdgcn_s_barrier();
        __builtin_amdgcn_s_setprio(1);
        quad(4, 0);
        __builtin_amdgcn_s_setprio(0);
        if (t + 1 < T) {
            if (t + 2 < T) asm volatile("s_waitcnt vmcnt(6)" ::: "memory");
            else           asm volatile("s_waitcnt vmcnt(0)" ::: "memory");
        }
        asm volatile("" ::: "memory");
        __builtin_amdgcn_s_barrier();
    }

    // ---- LDS-bounce epilogue: full-line coalesced stores ----
    __syncthreads();                              // LDS quiescent (drained at T-2's vmcnt(0))
    if constexpr (!OUT_FP32) {
        u16* l2 = (u16*)&lds[0][0][0];            // [256][256] bf16 = 128 KiB
#pragma unroll
        for (int j = 0; j < 4; ++j) {
            const int col = (wc << 6) + (j << 4) + fr;
#pragma unroll
            for (int i = 0; i < 8; ++i) {
                const int row0 = (wr << 7) + (i << 4) + (fq << 2);
#pragma unroll
                for (int r = 0; r < 4; ++r)
                    l2[(row0 + r) * 256 + col] = f2bf(acc[i][j][r]);
            }
        }
        __syncthreads();
        u16* C = (u16*)Cv + (long)bz * sC;
#pragma unroll
        for (int it = 0; it < 16; ++it) {
            const int row = it * 16 + (tid >> 5);
            const int ch  = tid & 31;
            const short8 v = *(const short8*)&l2[row * 256 + ch * 8];
            *(short8*)&C[(tileM + row) * (long)ldc + tileN + ch * 8] = v;
        }
    } else {
        float* l2f = (float*)&lds[0][0][0];       // [128][256] fp32 = 128 KiB per pass
        float* C = (float*)Cv + (long)bz * sC;
#pragma unroll
        for (int pass = 0; pass < 2; ++pass) {
            if (pass) __syncthreads();
            if (wr == pass) {
#pragma unroll
                for (int j = 0; j < 4; ++j) {
                    const int col = (wc << 6) + (j << 4) + fr;
#pragma unroll
                    for (int i = 0; i < 8; ++i) {
                        const int row0 = (i << 4) + (fq << 2);
#pragma unroll
                        for (int r = 0; r < 4; ++r)
                            l2f[(row0 + r) * 256 + col] = acc[i][j][r];
                    }
                }
            }
            __syncthreads();
#pragma unroll
            for (int it = 0; it < 16; ++it) {
                const int row = it * 8 + (tid >> 6);
                const int ch  = tid & 63;
                const float4 v = *(const float4*)&l2f[row * 256 + ch * 4];
                *(float4*)&C[(tileM + pass * 128 + row) * (long)ldc + tileN + ch * 4] = v;
            }
        }
    }
}

// ===================== fused 3-projection GEMM: [Q|K|V] = A(16384x1024) * Wcat(3072x1024)^T =====================
// Same K-loop; LDS-bounce epilogue; K-lockstep XCD window mapping (8bx x 4by windows per XCD).
__global__ __launch_bounds__(512, 2) void gemm_proj3(
    const u16* __restrict__ A, const u16* __restrict__ Bm,
    const float* __restrict__ bcat,
    u16* __restrict__ Pq, u16* __restrict__ Pk, u16* __restrict__ Pv, int K)
{
    __shared__ __align__(16) u16 lds[2][2][256 * 64];
    const int tid  = threadIdx.x;
    const int lane = tid & 63;
    const int wv   = tid >> 6;
    const int wr   = wv >> 2;
    const int wc   = wv & 3;
    const int fr   = lane & 15, fq = lane >> 4;

    // grid (64,12). XCD x owns a 16bx x 6by super-tile; co-resident 32 blocks form
    // 8x4 (then 16x2) windows -> same-K panel slices L2-resident (round-4: 32 disjoint
    // A-panels = 16MB blew the 4MB L2; FETCH 203MB vs 38 ideal).
    const int bid = blockIdx.x + 64 * blockIdx.y;
    const int x  = bid & 7, l = bid >> 3;        // XCD, local 0..95
    const int x0 = (x & 3) * 16, y0 = (x >> 2) * 6;
    const int w = l >> 5, r = l & 31;
    int bx, by;
    if (w == 0)      { bx = x0 + (r & 7);      by = y0 + (r >> 3); }
    else if (w == 1) { bx = x0 + 8 + (r & 7);  by = y0 + (r >> 3); }
    else             { bx = x0 + (r & 15);     by = y0 + 4 + (r >> 4); }

    const long tileM = (long)bx * 256, tileN = (long)by * 256;
    const int T = K >> 6;

    floatx4 acc[8][4];
#pragma unroll
    for (int i = 0; i < 8; ++i)
#pragma unroll
        for (int j = 0; j < 4; ++j) acc[i][j] = (floatx4){0.f, 0.f, 0.f, 0.f};

    const int lrow = lane >> 3;
    const int scol = ((lane & 7) ^ lrow) << 3;
    const int sw   = fr & 7;
    const int kc0  = ((fq ^ sw) << 3);
    const int kc1  = (((4 + fq) ^ sw) << 3);

    auto stage = [&](int tt, int side, int hh, int bb) {
#pragma unroll
        for (int i = 0; i < 2; ++i) {
            const int j = i * 8 + wv;
            const int prow = side ? (((j >> 2) << 6) + (hh << 5) + ((j & 3) << 3))
                                  : (((j >> 3) << 7) + (hh << 6) + ((j & 7) << 3));
            const u16* src = side ? Bm : A;
            const long rb  = side ? tileN : tileM;
            g2lds16(src + (size_t)(rb + prow + lrow) * (size_t)K + (size_t)(tt << 6) + scol,
                    &lds[bb][side][prow * 64]);
        }
    };

    short8 Af[4][2], Bf[4][2];
    auto quad = [&](int mb, int nb) {
#pragma unroll
        for (int m = 0; m < 4; ++m)
#pragma unroll
            for (int n = 0; n < 2; ++n) {
                acc[mb + m][nb + n] = __builtin_amdgcn_mfma_f32_16x16x32_bf16(
                    Af[m][0], Bf[nb + n][0], acc[mb + m][nb + n], 0, 0, 0);
                acc[mb + m][nb + n] = __builtin_amdgcn_mfma_f32_16x16x32_bf16(
                    Af[m][1], Bf[nb + n][1], acc[mb + m][nb + n], 0, 0, 0);
            }
    };

    stage(0, 0, 0, 0); stage(0, 1, 0, 0); stage(0, 1, 1, 0); stage(0, 0, 1, 0);
    stage(1, 0, 0, 1); stage(1, 1, 1, 1); stage(1, 0, 1, 1);
    asm volatile("s_waitcnt vmcnt(6)" ::: "memory");
    __builtin_amdgcn_s_barrier();

    for (int t = 0; t < T; ++t) {
        const int cb = t & 1;
        const u16* lA = &lds[cb][0][0];
        const u16* lB = &lds[cb][1][0];

#pragma unroll
        for (int m = 0; m < 4; ++m) {
            const int ro = ((wr << 7) + (m << 4) + fr) * 64;
            Af[m][0] = *(const short8*)&lA[ro + kc0];
            Af[m][1] = *(const short8*)&lA[ro + kc1];
        }
#pragma unroll
        for (int n = 0; n < 2; ++n) {
            const int ro = ((wc << 6) + (n << 4) + fr) * 64;
            Bf[n][0] = *(const short8*)&lB[ro + kc0];
            Bf[n][1] = *(const short8*)&lB[ro + kc1];
        }
        if (t + 1 < T) stage(t + 1, 1, 0, cb ^ 1);
        asm volatile("" ::: "memory");
        __builtin_amdgcn_s_barrier();
        asm volatile("s_waitcnt lgkmcnt(0)" ::: "memory");
        __builtin_amdgcn_sched_barrier(0);
        __builtin_amdgcn_s_setprio(1);
        quad(0, 0);
        __builtin_amdgcn_s_setprio(0);
        asm volatile("" ::: "memory");
        __builtin_amdgcn_s_barrier();

#pragma unroll
        for (int n = 2; n < 4; ++n) {
            const int ro = ((wc << 6) + (n << 4) + fr) * 64;
            Bf[n][0] = *(const short8*)&lB[ro + kc0];
            Bf[n][1] = *(const short8*)&lB[ro + kc1];
        }
        if (t + 2 < T) stage(t + 2, 0, 0, cb);
        asm volatile("" ::: "memory");
        __builtin_amdgcn_s_barrier();
        asm volatile("s_waitcnt lgkmcnt(0)" ::: "memory");
        __builtin_amdgcn_sched_barrier(0);
        __builtin_amdgcn_s_setprio(1);
        quad(0, 2);
        __builtin_amdgcn_s_setprio(0);
        asm volatile("" ::: "memory");
        __builtin_amdgcn_s_barrier();

#pragma unroll
        for (int m = 0; m < 4; ++m) {
            const int ro = ((wr << 7) + ((m + 4) << 4) + fr) * 64;
            Af[m][0] = *(const short8*)&lA[ro + kc0];
            Af[m][1] = *(const short8*)&lA[ro + kc1];
        }
        if (t + 2 < T) stage(t + 2, 1, 1, cb);
        asm volatile("" ::: "memory");
        __builtin_amdgcn_s_barrier();
        asm volatile("s_waitcnt lgkmcnt(0)" ::: "memory");
        __builtin_amdgcn_sched_barrier(0);
        __builtin_amdgcn_s_setprio(1);
        quad(4, 2);
        __builtin_amdgcn_s_setprio(0);
        asm volatile("" ::: "memory");
        __builtin_amdgcn_s_barrier();

        if (t + 2 < T) stage(t + 2, 0, 1, cb);
        asm volatile("" ::: "memory");
        __builtin_amdgcn_s_barrier();
        __builtin_amdgcn_s_setprio(1);
        quad(4, 0);
        __builtin_amdgcn_s_setprio(0);
        if (t + 1 < T) {
            if (t + 2 < T) asm volatile("s_waitcnt vmcnt(6)" ::: "memory");
            else           asm volatile("s_waitcnt vmcnt(0)" ::: "memory");
        }
        asm volatile("" ::: "memory");
        __builtin_amdgcn_s_barrier();
    }

    // ---- LDS-bounce epilogue ----
    const int oid = (int)(tileN >> 10);           // block-uniform output id
    __syncthreads();
    if (oid < 2) {
        // row-major bf16
        u16* l2 = (u16*)&lds[0][0][0];            // [256][256]
#pragma unroll
        for (int j = 0; j < 4; ++j) {
            const int col = (wc << 6) + (j << 4) + fr;
            const float bv = bcat[tileN + col];
#pragma unroll
            for (int i = 0; i < 8; ++i) {
                const int row0 = (wr << 7) + (i << 4) + (fq << 2);
#pragma unroll
                for (int r = 0; r < 4; ++r)
                    l2[(row0 + r) * 256 + col] = f2bf(acc[i][j][r] + bv);
            }
        }
        __syncthreads();
        u16* P = oid ? Pk : Pq;
        const long colN = tileN & 1023;
#pragma unroll
        for (int it = 0; it < 16; ++it) {
            const int row = it * 16 + (tid >> 5);
            const int ch  = tid & 31;
            const short8 v = *(const short8*)&l2[row * 256 + ch * 8];
            *(short8*)&P[(tileM + row) * (long)Dd + colN + ch * 8] = v;
        }
    } else {
        // transposed bf16 -> Pv[b][col][m]; LDS [col][row] with XOR bank swizzle
        char* l2c = (char*)&lds[0][0][0];
#pragma unroll
        for (int j = 0; j < 4; ++j) {
            const int col = (wc << 6) + (j << 4) + fr;
            const float bv = bcat[tileN + col];
            const int swz = (col & 7) << 4;
#pragma unroll
            for (int i = 0; i < 8; ++i) {
                const int row0 = (wr << 7) + (i << 4) + (fq << 2);
                const u64 pk = (u64)f2bf(acc[i][j][0] + bv)
                             | ((u64)f2bf(acc[i][j][1] + bv) << 16)
                             | ((u64)f2bf(acc[i][j][2] + bv) << 32)
                             | ((u64)f2bf(acc[i][j][3] + bv) << 48);
                *(u64*)(l2c + col * 512 + ((row0 * 2) ^ swz)) = pk;
            }
        }
        __syncthreads();
        const long b  = tileM >> 10, tm = tileM & 1023;
        const long colN = tileN & 1023;
#pragma unroll
        for (int it = 0; it < 16; ++it) {
            const int col = it * 16 + (tid >> 5);
            const int ch  = tid & 31;
            const short8 v = *(const short8*)(l2c + col * 512 + ((ch * 16) ^ ((col & 7) << 4)));
            *(short8*)&Pv[b * sMDc + (colN + col) * (long)Mm + tm + ch * 8] = v;
        }
    }
}

// ---------------- fused fp32->bf16 conversion + column-mean pooling ----------------
__global__ __launch_bounds__(256) void conv_pool(
    const float* __restrict__ oV, const float* __restrict__ oT,
    u16* __restrict__ oVb, u16* __restrict__ oTb,
    float* __restrict__ vpool, float* __restrict__ tpool)
{
    const int b = blockIdx.y, srci = blockIdx.z;
    const float* src = (srci ? oT : oV) + (size_t)b * Mm * Dd;
    u16* dst = (srci ? oTb : oVb) + (size_t)b * Mm * Dd;
    const int c4 = threadIdx.x * 4;
    const int r0 = blockIdx.x * 64;
    float4 s = {0.f, 0.f, 0.f, 0.f};
    for (int r = r0; r < r0 + 64; ++r) {
        const float4 v = *(const float4*)&src[(size_t)r * Dd + c4];
        s.x += v.x; s.y += v.y; s.z += v.z; s.w += v.w;
        ushort4 o;
        o.x = f2bf(v.x); o.y = f2bf(v.y); o.z = f2bf(v.z); o.w = f2bf(v.w);
        *(ushort4*)&dst[(size_t)r * Dd + c4] = o;
    }
    float* pool = (srci ? tpool : vpool) + (size_t)b * Dd + c4;
    atomicAdd(pool + 0, s.x * (1.0f / Mm));
    atomicAdd(pool + 1, s.y * (1.0f / Mm));
    atomicAdd(pool + 2, s.z * (1.0f / Mm));
    atomicAdd(pool + 3, s.w * (1.0f / Mm));
}

// ---------------- 6x weight fp32 -> bf16 (one launch) ----------------
__global__ __launch_bounds__(256) void wconv6(
    const float* __restrict__ w0, const float* __restrict__ w1, const float* __restrict__ w2,
    const float* __restrict__ w3, const float* __restrict__ w4, const float* __restrict__ w5,
    u16* __restrict__ dst)
{
    const float* src;
    switch (blockIdx.y) {
        case 0: src = w0; break; case 1: src = w1; break; case 2: src = w2; break;
        case 3: src = w3; break; case 4: src = w4; break; default: src = w5; break;
    }
    const size_t i = (size_t)blockIdx.x * 256 + threadIdx.x;
    const float4 a = ((const float4*)src)[2 * i];
    const float4 b = ((const float4*)src)[2 * i + 1];
    short8 o;
    o[0]=(short)f2bf(a.x); o[1]=(short)f2bf(a.y); o[2]=(short)f2bf(a.z); o[3]=(short)f2bf(a.w);
    o[4]=(short)f2bf(b.x); o[5]=(short)f2bf(b.y); o[6]=(short)f2bf(b.z); o[7]=(short)f2bf(b.w);
    *(short8*)(dst + (((size_t)blockIdx.y) << 20) + 8 * i) = o;
}

// ---------------- concat 6 bias vectors -> bcat[6144] ----------------
__global__ __launch_bounds__(256) void bcat_kernel(
    const float* __restrict__ b0, const float* __restrict__ b1, const float* __restrict__ b2,
    const float* __restrict__ b3, const float* __restrict__ b4, const float* __restrict__ b5,
    float* __restrict__ out)
{
    const int i = blockIdx.x * 256 + threadIdx.x;
    const int seg = i >> 10;
    const float* s;
    switch (seg) {
        case 0: s = b0; break; case 1: s = b1; break; case 2: s = b2; break;
        case 3: s = b3; break; case 4: s = b4; break; default: s = b5; break;
    }
    out[i] = s[i & 1023];
}

// ---------------- FFN ----------------
__global__ __launch_bounds__(256) void ffn1_kernel(
    const float* __restrict__ vpool, const float* __restrict__ tpool,
    const float* __restrict__ f1w, const float* __restrict__ f1b,
    float* __restrict__ hbuf)
{
    const int j = blockIdx.x, b = blockIdx.y;
    const int t = threadIdx.x, wv = t >> 6, lane = t & 63;
    __shared__ float red[4];
    const float* w = f1w + (size_t)j * (2 * Dd);
    float a = 0.f;
    for (int k = t; k < Dd; k += 256) a += vpool[b * Dd + k] * w[k];
    for (int k = t; k < Dd; k += 256) a += tpool[b * Dd + k] * w[Dd + k];
    a = waveSum(a);
    if (lane == 0) red[wv] = a;
    __syncthreads();
    if (t == 0) hbuf[b * HIDh + j] = fmaxf(red[0] + red[1] + red[2] + red[3] + f1b[j], 0.0f);
}

__global__ __launch_bounds__(256) void ffn2_kernel(
    const float* __restrict__ hbuf, const float* __restrict__ f2w,
    const float* __restrict__ f2b, float* __restrict__ lbuf)
{
    const int b = blockIdx.x;
    const int t = threadIdx.x, wv = t >> 6, lane = t & 63;
    __shared__ float red[4];
    float p = 0.f;
    for (int j = t; j < HIDh; j += 256) p += hbuf[b * HIDh + j] * f2w[j];
    p = waveSum(p);
    if (lane == 0) red[wv] = p;
    __syncthreads();
    if (t == 0) {
        const float z = red[0] + red[1] + red[2] + red[3] + f2b[0];
        lbuf[b] = 1.0f / (1.0f + expf(-z));
    }
}

// ---------------- sim softmax -> fp32 mask (d_out) ----------------
__global__ __launch_bounds__(256) void sim_softmax_mask(
    const u16* __restrict__ scores, const float* __restrict__ lbuf, float* __restrict__ maskF)
{
    const int row = blockIdx.x, b = blockIdx.y;
    const int t = threadIdx.x, wv = t >> 6, lane = t & 63;
    __shared__ float red[8];
    const size_t off = ((size_t)b * Mm + row) * Nn;
    const uint2 sv = *(const uint2*)(scores + off + 4 * t);
    const float x0 = bf2f((u16)(sv.x & 0xFFFFu)) * INV_SQRT_D;
    const float x1 = bf2f((u16)(sv.x >> 16))     * INV_SQRT_D;
    const float x2 = bf2f((u16)(sv.y & 0xFFFFu)) * INV_SQRT_D;
    const float x3 = bf2f((u16)(sv.y >> 16))     * INV_SQRT_D;
    float mx = waveMax(fmaxf(fmaxf(x0, x1), fmaxf(x2, x3)));
    if (lane == 0) red[wv] = mx;
    __syncthreads();
    mx = fmaxf(fmaxf(red[0], red[1]), fmaxf(red[2], red[3]));
    const float e0 = expf(x0 - mx), e1 = expf(x1 - mx), e2 = expf(x2 - mx), e3 = expf(x3 - mx);
    float s = waveSum(e0 + e1 + e2 + e3);
    if (lane == 0) red[4 + wv] = s;
    __syncthreads();
    const float inv = 1.0f / fmaxf(red[4] + red[5] + red[6] + red[7], 1e-30f);
    const float l = lbuf[b];
    float4 mk;
    mk.x = (e0 * inv >= l) ? 1.0f : 0.0f;
    mk.y = (e1 * inv >= l) ? 1.0f : 0.0f;
    mk.z = (e2 * inv >= l) ? 1.0f : 0.0f;
    mk.w = (e3 * inv >= l) ? 1.0f : 0.0f;
    *(float4*)(maskF + off + 4 * t) = mk;
}

// ---------------- mask transpose: fp32 mask[b][m][n] -> u8 maskT[b][n][m] ----------------
__global__ __launch_bounds__(256) void transpose_mask(
    const float* __restrict__ maskF, u8* __restrict__ maskT)
{
    __shared__ u8 tile[64][68];
    const int m0 = blockIdx.x * 64, n0 = blockIdx.y * 64, b = blockIdx.z;
    const int t = threadIdx.x;
    const int r = t >> 2, c = (t & 3) * 16;
    const float* src = maskF + ((size_t)b * Mm + (m0 + r)) * Nn + n0 + c;
    float4 f0 = ((const float4*)src)[0];
    float4 f1 = ((const float4*)src)[1];
    float4 f2 = ((const float4*)src)[2];
    float4 f3 = ((const float4*)src)[3];
    u8* dst = &tile[r][c];
    dst[0]=f0.x!=0.f; dst[1]=f0.y!=0.f; dst[2]=f0.z!=0.f; dst[3]=f0.w!=0.f;
    dst[4]=f1.x!=0.f; dst[5]=f1.y!=0.f; dst[6]=f1.z!=0.f; dst[7]=f1.w!=0.f;
    dst[8]=f2.x!=0.f; dst[9]=f2.y!=0.f; dst[10]=f2.z!=0.f; dst[11]=f2.w!=0.f;
    dst[12]=f3.x!=0.f; dst[13]=f3.y!=0.f; dst[14]=f3.z!=0.f; dst[15]=f3.w!=0.f;
    __syncthreads();
    union { u8 b[16]; uint4 v; } pk;
#pragma unroll
    for (int k = 0; k < 16; ++k) pk.b[k] = tile[c + k][r];
    *(uint4*)(maskT + ((size_t)b * Nn + (n0 + r)) * Mm + m0 + c) = pk.v;
}

// ---------------- masked softmax over bf16 scores, IN-PLACE -> bf16 attn ----------------
template <bool TRANSP>
__global__ __launch_bounds__(256) void masked_softmax(
    u16* __restrict__ scores, const float* __restrict__ maskF, const u8* __restrict__ maskT)
{
    const int row = blockIdx.x, b = blockIdx.y;
    const int t = threadIdx.x, wv = t >> 6, lane = t & 63;
    __shared__ float red[8];
    const size_t off = ((size_t)b * Mm + row) * Nn;
    const uint2 sv = *(const uint2*)(scores + off + 4 * t);
    float x0 = bf2f((u16)(sv.x & 0xFFFFu)) * INV_SQRT_D;
    float x1 = bf2f((u16)(sv.x >> 16))     * INV_SQRT_D;
    float x2 = bf2f((u16)(sv.y & 0xFFFFu)) * INV_SQRT_D;
    float x3 = bf2f((u16)(sv.y >> 16))     * INV_SQRT_D;
    if (TRANSP) {
        const u32 mk = *(const u32*)(maskT + off + 4 * t);
        if (!(mk & 0x000000FFu)) x0 = NEGINF;
        if (!(mk & 0x0000FF00u)) x1 = NEGINF;
        if (!(mk & 0x00FF0000u)) x2 = NEGINF;
        if (!(mk & 0xFF000000u)) x3 = NEGINF;
    } else {
        const float4 mk = *(const float4*)(maskF + off + 4 * t);
        if (mk.x == 0.f) x0 = NEGINF;
        if (mk.y == 0.f) x1 = NEGINF;
        if (mk.z == 0.f) x2 = NEGINF;
        if (mk.w == 0.f) x3 = NEGINF;
    }
    float mx = waveMax(fmaxf(fmaxf(x0, x1), fmaxf(x2, x3)));
    if (lane == 0) red[wv] = mx;
    __syncthreads();
    mx = fmaxf(fmaxf(red[0], red[1]), fmaxf(red[2], red[3]));
    const float e0 = expf(x0 - mx), e1 = expf(x1 - mx), e2 = expf(x2 - mx), e3 = expf(x3 - mx);
    float s = waveSum(e0 + e1 + e2 + e3);
    if (lane == 0) red[4 + wv] = s;
    __syncthreads();
    const float inv = 1.0f / fmaxf(red[4] + red[5] + red[6] + red[7], 1e-30f);
    uint2 pk;
    pk.x = (u32)f2bf(e0 * inv) | ((u32)f2bf(e1 * inv) << 16);
    pk.y = (u32)f2bf(e2 * inv) | ((u32)f2bf(e3 * inv) << 16);
    *(uint2*)(scores + off + 4 * t) = pk;
}

extern "C" void kernel_launch(void* const* d_in, const int* in_sizes, int n_in,
                              void* d_out, int out_size, void* d_ws, size_t ws_size,
                              hipStream_t stream)
{
    (void)in_sizes; (void)n_in; (void)out_size; (void)ws_size;
    const float* oV     = (const float*)d_in[0];
    const float* oT     = (const float*)d_in[1];
    const float* Wq_v_w = (const float*)d_in[2];
    const float* Wq_v_b = (const float*)d_in[3];
    const float* Wk_t_w = (const float*)d_in[4];
    const float* Wk_t_b = (const float*)d_in[5];
    const float* Wv_t_w = (const float*)d_in[6];
    const float* Wv_t_b = (const float*)d_in[7];
    const float* Wq_t_w = (const float*)d_in[8];
    const float* Wq_t_b = (const float*)d_in[9];
    const float* Wk_v_w = (const float*)d_in[10];
    const float* Wk_v_b = (const float*)d_in[11];
    const float* Wv_v_w = (const float*)d_in[12];
    const float* Wv_v_b = (const float*)d_in[13];
    const float* f1w    = (const float*)d_in[14];
    const float* f1b    = (const float*)d_in[15];
    const float* f2w    = (const float*)d_in[16];
    const float* f2b    = (const float*)d_in[17];

    float* out_vt = (float*)d_out;
    float* out_tv = out_vt + BMDc;
    float* maskF  = out_vt + 2 * BMDc;

    // workspace layout (~320 MB of 768 MB)
    u16* S0a = (u16*)d_ws;                       // Qv                  32 MB
    u16* S1a = S0a + BMDc;                       // Kt                  32 MB
    u16* S2a = S1a + BMDc;                       // Vt^T                32 MB
    u16* S0b = S2a + BMDc;                       // Qt                  32 MB
    u16* S1b = S0b + BMDc;                       // Kv                  32 MB
    u16* S2b = S1b + BMDc;                       // Vv^T                32 MB
    u16* S3  = S2b + BMDc;                       // scores/attn         32 MB
    u16* oVb = S3 + BMDc;                        // bf16 oV             32 MB
    u16* oTb = oVb + BMDc;                       // bf16 oT             32 MB
    u16* Wc  = oTb + BMDc;                       // 6x bf16 weights     12 MB
    u8*  maskT = (u8*)(Wc + 6 * (1 << 20));      // transposed u8 mask  16 MB
    float* bcat  = (float*)(maskT + BMDc);       // 6144 floats
    float* vpool = bcat + 6144;
    float* tpool = vpool + Bz * Dd;
    float* hbuf  = tpool + Bz * Dd;
    float* lbuf  = hbuf + Bz * HIDh;

    const dim3 blk(256), blk512(512);
    const dim3 gBat(Mm / 256, Nn / 256, Bz);           // (4,4,16) = 256 wg
    const dim3 gFproj(64, 12, 1);                      // 768 wg
    const dim3 gRow(Mm, Bz);
    const dim3 gTrp(Mm / 64, Nn / 64, Bz);
    const long sMD = sMDc, sMN = (long)Mm * Nn;

    // 0: weights + biases to bf16/concat
    wconv6<<<dim3(512, 6), blk, 0, stream>>>(Wq_v_w, Wk_v_w, Wv_v_w, Wq_t_w, Wk_t_w, Wv_t_w, Wc);
    bcat_kernel<<<dim3(24), blk, 0, stream>>>(Wq_v_b, Wk_v_b, Wv_v_b, Wq_t_b, Wk_t_b, Wv_t_b, bcat);

    // 1: fused convert + pool
    hipMemsetAsync(vpool, 0, 2 * Bz * Dd * sizeof(float), stream);
    conv_pool<<<dim3(16, Bz, 2), blk, 0, stream>>>(oV, oT, oVb, oTb, vpool, tpool);
    ffn1_kernel<<<dim3(HIDh, Bz), blk, 0, stream>>>(vpool, tpool, f1w, f1b, hbuf);
    ffn2_kernel<<<dim3(Bz), blk, 0, stream>>>(hbuf, f2w, f2b, lbuf);

    // 2: sim scores -> mask (fp32 out) -> transposed u8 mask
    gemm256<false><<<gBat, blk512, 0, stream>>>(oVb, oTb, S3, Dd, Nn, sMD, sMD, sMN);
    sim_softmax_mask<<<gRow, blk, 0, stream>>>(S3, lbuf, maskF);
    transpose_mask<<<gTrp, blk, 0, stream>>>(maskF, maskT);

    // 3: fused projections.  A=oVb -> {Qv->S0a, Kv->S1b, Vv^T->S2b};  A=oTb -> {Qt->S0b, Kt->S1a, Vt^T->S2a}
    gemm_proj3<<<gFproj, blk512, 0, stream>>>(oVb, Wc,                 bcat,        S0a, S1b, S2b, Dd);
    gemm_proj3<<<gFproj, blk512, 0, stream>>>(oTb, Wc + 3 * (1 << 20), bcat + 3072, S0b, S1a, S2a, Dd);

    // 4: V->T attention
    gemm256<false><<<gBat, blk512, 0, stream>>>(S0a, S1a, S3, Dd, Nn, sMD, sMD, sMN);
    masked_softmax<false><<<gRow, blk, 0, stream>>>(S3, maskF, maskT);
    gemm256<true ><<<gBat, blk512, 0, stream>>>(S3, S2a, out_vt, Nn, Dd, sMN, sMD, sMD);

    // 5: T->V attention
    gemm256<false><<<gBat, blk512, 0, stream>>>(S0b, S1b, S3, Dd, Nn, sMD, sMD, sMN);
    masked_softmax<true><<<gRow, blk, 0, stream>>>(S3, maskF, maskT);
    gemm256<true ><<<gBat, blk512, 0, stream>>>(S3, S2b, out_tv, Nn, Dd, sMN, sMD, sMD);
}

// Round 6
// 816.770 us; speedup vs baseline: 1.2380x; 1.0121x over previous
//
#include <hip/hip_runtime.h>
#include <stdint.h>

typedef unsigned short u16;
typedef unsigned char  u8;
typedef unsigned int   u32;
typedef unsigned long long u64;
typedef __attribute__((ext_vector_type(8))) short  short8;
typedef __attribute__((ext_vector_type(4))) float  floatx4;

#define Bz   16
#define Mm   1024
#define Nn   1024
#define Dd   1024
#define HIDh 512
#define INV_SQRT_D 0.03125f
#define NEGINF (-1.0e9f)
#define BMDc  ((size_t)Bz * Mm * Dd)
#define sMDc  ((long)Mm * Dd)

__device__ __forceinline__ float bf2f(u16 h) {
    union { u32 u; float f; } c; c.u = ((u32)h) << 16; return c.f;
}
__device__ __forceinline__ u16 f2bf(float f) {
    union { float f; u32 u; } c; c.f = f;
    u32 u = c.u;
    return (u16)((u + 0x7FFFu + ((u >> 16) & 1u)) >> 16);
}
__device__ __forceinline__ void g2lds16(const u16* g, u16* l) {
    __builtin_amdgcn_global_load_lds((const __attribute__((address_space(1))) void*)g,
                                     (__attribute__((address_space(3))) void*)l, 16, 0, 0);
}

__device__ __forceinline__ float waveSum(float v) {
#pragma unroll
    for (int o = 32; o > 0; o >>= 1) v += __shfl_xor(v, o);
    return v;
}
__device__ __forceinline__ float waveMax(float v) {
#pragma unroll
    for (int o = 32; o > 0; o >>= 1) v = fmaxf(v, __shfl_xor(v, o));
    return v;
}

// ===================== 256x256 8-phase GEMM:  C = A * B^T  (bf16 in, fp32 acc) =====================
// K-loop verified rounds 2/4/5 (conflict-free). Dual pointer sets: branch = bz>>4 (merged dispatches).
// Epilogue: LDS bounce with rotation swizzle (round-5 counters: 1.31M conflicts from unswizzled bounce).
template <bool OUT_FP32>
__global__ __launch_bounds__(512, 2) void gemm256(
    const u16* __restrict__ Aa, const u16* __restrict__ Ba, void* __restrict__ Ca,
    const u16* __restrict__ Ab, const u16* __restrict__ Bb, void* __restrict__ Cb,
    int K, int ldc, long sA, long sB, long sC)
{
    __shared__ __align__(16) u16 lds[2][2][256 * 64];
    const int tid  = threadIdx.x;
    const int lane = tid & 63;
    const int wv   = tid >> 6;
    const int wr   = wv >> 2;
    const int wc   = wv & 3;
    const int fr   = lane & 15, fq = lane >> 4;

    const int gX = gridDim.x, gY = gridDim.y;
    int bid = blockIdx.x + gX * (blockIdx.y + gY * blockIdx.z);
    const int nwg = gX * gY * gridDim.z;
    int wg = (bid & 7) * (nwg >> 3) + (bid >> 3);
    const int bx = wg % gX; wg /= gX;
    const int by = wg % gY;
    const int bz2 = wg / gY;
    const int br = bz2 >> 4;            // branch (0 unless merged 32-z grid)
    const int bz = bz2 & 15;

    const u16* A  = (br ? Ab : Aa) + (long)bz * sA;
    const u16* Bm = (br ? Bb : Ba) + (long)bz * sB;
    void* Cv = br ? Cb : Ca;

    const long tileM = (long)bx * 256, tileN = (long)by * 256;
    const int T = K >> 6;

    floatx4 acc[8][4];
#pragma unroll
    for (int i = 0; i < 8; ++i)
#pragma unroll
        for (int j = 0; j < 4; ++j) acc[i][j] = (floatx4){0.f, 0.f, 0.f, 0.f};

    const int lrow = lane >> 3;
    const int scol = ((lane & 7) ^ lrow) << 3;
    const int sw   = fr & 7;
    const int kc0  = ((fq ^ sw) << 3);
    const int kc1  = (((4 + fq) ^ sw) << 3);

    auto stage = [&](int tt, int side, int hh, int bb) {
#pragma unroll
        for (int i = 0; i < 2; ++i) {
            const int j = i * 8 + wv;
            const int prow = side ? (((j >> 2) << 6) + (hh << 5) + ((j & 3) << 3))
                                  : (((j >> 3) << 7) + (hh << 6) + ((j & 7) << 3));
            const u16* src = side ? Bm : A;
            const long rb  = side ? tileN : tileM;
            g2lds16(src + (size_t)(rb + prow + lrow) * (size_t)K + (size_t)(tt << 6) + scol,
                    &lds[bb][side][prow * 64]);
        }
    };

    short8 Af[4][2], Bf[4][2];
    auto quad = [&](int mb, int nb) {
#pragma unroll
        for (int m = 0; m < 4; ++m)
#pragma unroll
            for (int n = 0; n < 2; ++n) {
                acc[mb + m][nb + n] = __builtin_amdgcn_mfma_f32_16x16x32_bf16(
                    Af[m][0], Bf[nb + n][0], acc[mb + m][nb + n], 0, 0, 0);
                acc[mb + m][nb + n] = __builtin_amdgcn_mfma_f32_16x16x32_bf16(
                    Af[m][1], Bf[nb + n][1], acc[mb + m][nb + n], 0, 0, 0);
            }
    };

    stage(0, 0, 0, 0); stage(0, 1, 0, 0); stage(0, 1, 1, 0); stage(0, 0, 1, 0);
    stage(1, 0, 0, 1); stage(1, 1, 1, 1); stage(1, 0, 1, 1);
    asm volatile("s_waitcnt vmcnt(6)" ::: "memory");
    __builtin_amdgcn_s_barrier();

    for (int t = 0; t < T; ++t) {
        const int cb = t & 1;
        const u16* lA = &lds[cb][0][0];
        const u16* lB = &lds[cb][1][0];

#pragma unroll
        for (int m = 0; m < 4; ++m) {
            const int ro = ((wr << 7) + (m << 4) + fr) * 64;
            Af[m][0] = *(const short8*)&lA[ro + kc0];
            Af[m][1] = *(const short8*)&lA[ro + kc1];
        }
#pragma unroll
        for (int n = 0; n < 2; ++n) {
            const int ro = ((wc << 6) + (n << 4) + fr) * 64;
            Bf[n][0] = *(const short8*)&lB[ro + kc0];
            Bf[n][1] = *(const short8*)&lB[ro + kc1];
        }
        if (t + 1 < T) stage(t + 1, 1, 0, cb ^ 1);
        asm volatile("" ::: "memory");
        __builtin_amdgcn_s_barrier();
        asm volatile("s_waitcnt lgkmcnt(0)" ::: "memory");
        __builtin_amdgcn_sched_barrier(0);
        __builtin_amdgcn_s_setprio(1);
        quad(0, 0);
        __builtin_amdgcn_s_setprio(0);
        asm volatile("" ::: "memory");
        __builtin_amdgcn_s_barrier();

#pragma unroll
        for (int n = 2; n < 4; ++n) {
            const int ro = ((wc << 6) + (n << 4) + fr) * 64;
            Bf[n][0] = *(const short8*)&lB[ro + kc0];
            Bf[n][1] = *(const short8*)&lB[ro + kc1];
        }
        if (t + 2 < T) stage(t + 2, 0, 0, cb);
        asm volatile("" ::: "memory");
        __builtin_amdgcn_s_barrier();
        asm volatile("s_waitcnt lgkmcnt(0)" ::: "memory");
        __builtin_amdgcn_sched_barrier(0);
        __builtin_amdgcn_s_setprio(1);
        quad(0, 2);
        __builtin_amdgcn_s_setprio(0);
        asm volatile("" ::: "memory");
        __builtin_amdgcn_s_barrier();

#pragma unroll
        for (int m = 0; m < 4; ++m) {
            const int ro = ((wr << 7) + ((m + 4) << 4) + fr) * 64;
            Af[m][0] = *(const short8*)&lA[ro + kc0];
            Af[m][1] = *(const short8*)&lA[ro + kc1];
        }
        if (t + 2 < T) stage(t + 2, 1, 1, cb);
        asm volatile("" ::: "memory");
        __builtin_amdgcn_s_barrier();
        asm volatile("s_waitcnt lgkmcnt(0)" ::: "memory");
        __builtin_amdgcn_sched_barrier(0);
        __builtin_amdgcn_s_setprio(1);
        quad(4, 2);
        __builtin_amdgcn_s_setprio(0);
        asm volatile("" ::: "memory");
        __builtin_amdgcn_s_barrier();

        if (t + 2 < T) stage(t + 2, 0, 1, cb);
        asm volatile("" ::: "memory");
        __builtin_amdgcn_s_barrier();
        __builtin_amdgcn_s_setprio(1);
        quad(4, 0);
        __builtin_amdgcn_s_setprio(0);
        if (t + 1 < T) {
            if (t + 2 < T) asm volatile("s_waitcnt vmcnt(6)" ::: "memory");
            else           asm volatile("s_waitcnt vmcnt(0)" ::: "memory");
        }
        asm volatile("" ::: "memory");
        __builtin_amdgcn_s_barrier();
    }

    // ---- LDS-bounce epilogue (rotation-swizzled) ----
    __syncthreads();
    if constexpr (!OUT_FP32) {
        u16* l2 = (u16*)&lds[0][0][0];            // [256][32 chunks of 8]
#pragma unroll
        for (int j = 0; j < 4; ++j) {
            const int col = (wc << 6) + (j << 4) + fr;
            const int c   = col >> 3;
#pragma unroll
            for (int i = 0; i < 8; ++i) {
                const int row0 = (wr << 7) + (i << 4) + (fq << 2);
#pragma unroll
                for (int r = 0; r < 4; ++r) {
                    const int row = row0 + r;
                    l2[row * 256 + (((c + row) & 31) << 3) + (col & 7)] = f2bf(acc[i][j][r]);
                }
            }
        }
        __syncthreads();
        u16* C = (u16*)Cv + (long)bz * sC;
#pragma unroll
        for (int it = 0; it < 16; ++it) {
            const int row = it * 16 + (tid >> 5);
            const int ch  = tid & 31;
            const short8 v = *(const short8*)&l2[row * 256 + (((ch + row) & 31) << 3)];
            *(short8*)&C[(tileM + row) * (long)ldc + tileN + ch * 8] = v;
        }
    } else {
        float* l2f = (float*)&lds[0][0][0];       // [128][64 chunks of 4]
        float* C = (float*)Cv + (long)bz * sC;
#pragma unroll
        for (int pass = 0; pass < 2; ++pass) {
            if (pass) __syncthreads();
            if (wr == pass) {
#pragma unroll
                for (int j = 0; j < 4; ++j) {
                    const int col = (wc << 6) + (j << 4) + fr;
                    const int c   = col >> 2;
#pragma unroll
                    for (int i = 0; i < 8; ++i) {
                        const int row0 = (i << 4) + (fq << 2);
#pragma unroll
                        for (int r = 0; r < 4; ++r)
                            l2f[(row0 + r) * 256 + (((c + (fq << 2)) & 63) << 2) + (col & 3)] = acc[i][j][r];
                    }
                }
            }
            __syncthreads();
#pragma unroll
            for (int it = 0; it < 16; ++it) {
                const int row = it * 8 + (tid >> 6);
                const int ch  = tid & 63;
                const int rot = (row >> 2) & 3;
                const float4 v = *(const float4*)&l2f[row * 256 + (((ch + (rot << 2)) & 63) << 2)];
                *(float4*)&C[(tileM + pass * 128 + row) * (long)ldc + tileN + ch * 4] = v;
            }
        }
    }
}

// ===================== fused 3-projection GEMM (both inputs, grid 64x12x2) =====================
__global__ __launch_bounds__(512, 2) void gemm_proj3(
    const u16* __restrict__ A0, const u16* __restrict__ A1,
    const u16* __restrict__ Wcat, const float* __restrict__ bc,
    u16* __restrict__ Pq0, u16* __restrict__ Pk0, u16* __restrict__ Pv0,
    u16* __restrict__ Pq1, u16* __restrict__ Pk1, u16* __restrict__ Pv1, int K)
{
    __shared__ __align__(16) u16 lds[2][2][256 * 64];
    const int tid  = threadIdx.x;
    const int lane = tid & 63;
    const int wv   = tid >> 6;
    const int wr   = wv >> 2;
    const int wc   = wv & 3;
    const int fr   = lane & 15, fq = lane >> 4;

    const int z = blockIdx.z;
    const u16* A  = z ? A1 : A0;
    const u16* Bm = Wcat + ((size_t)z * 3 * Dd * Dd);
    const float* bcat = bc + z * 3072;
    u16* Pq = z ? Pq1 : Pq0;
    u16* Pk = z ? Pk1 : Pk0;
    u16* Pv = z ? Pv1 : Pv0;

    // K-lockstep XCD window (verified round 5: FETCH 203->86 MB)
    const int bid = blockIdx.x + 64 * blockIdx.y;
    const int x  = bid & 7, l = bid >> 3;
    const int x0 = (x & 3) * 16, y0 = (x >> 2) * 6;
    const int w = l >> 5, r = l & 31;
    int bx, by;
    if (w == 0)      { bx = x0 + (r & 7);      by = y0 + (r >> 3); }
    else if (w == 1) { bx = x0 + 8 + (r & 7);  by = y0 + (r >> 3); }
    else             { bx = x0 + (r & 15);     by = y0 + 4 + (r >> 4); }

    const long tileM = (long)bx * 256, tileN = (long)by * 256;
    const int T = K >> 6;

    floatx4 acc[8][4];
#pragma unroll
    for (int i = 0; i < 8; ++i)
#pragma unroll
        for (int j = 0; j < 4; ++j) acc[i][j] = (floatx4){0.f, 0.f, 0.f, 0.f};

    const int lrow = lane >> 3;
    const int scol = ((lane & 7) ^ lrow) << 3;
    const int sw   = fr & 7;
    const int kc0  = ((fq ^ sw) << 3);
    const int kc1  = (((4 + fq) ^ sw) << 3);

    auto stage = [&](int tt, int side, int hh, int bb) {
#pragma unroll
        for (int i = 0; i < 2; ++i) {
            const int j = i * 8 + wv;
            const int prow = side ? (((j >> 2) << 6) + (hh << 5) + ((j & 3) << 3))
                                  : (((j >> 3) << 7) + (hh << 6) + ((j & 7) << 3));
            const u16* src = side ? Bm : A;
            const long rb  = side ? tileN : tileM;
            g2lds16(src + (size_t)(rb + prow + lrow) * (size_t)K + (size_t)(tt << 6) + scol,
                    &lds[bb][side][prow * 64]);
        }
    };

    short8 Af[4][2], Bf[4][2];
    auto quad = [&](int mb, int nb) {
#pragma unroll
        for (int m = 0; m < 4; ++m)
#pragma unroll
            for (int n = 0; n < 2; ++n) {
                acc[mb + m][nb + n] = __builtin_amdgcn_mfma_f32_16x16x32_bf16(
                    Af[m][0], Bf[nb + n][0], acc[mb + m][nb + n], 0, 0, 0);
                acc[mb + m][nb + n] = __builtin_amdgcn_mfma_f32_16x16x32_bf16(
                    Af[m][1], Bf[nb + n][1], acc[mb + m][nb + n], 0, 0, 0);
            }
    };

    stage(0, 0, 0, 0); stage(0, 1, 0, 0); stage(0, 1, 1, 0); stage(0, 0, 1, 0);
    stage(1, 0, 0, 1); stage(1, 1, 1, 1); stage(1, 0, 1, 1);
    asm volatile("s_waitcnt vmcnt(6)" ::: "memory");
    __builtin_amdgcn_s_barrier();

    for (int t = 0; t < T; ++t) {
        const int cb = t & 1;
        const u16* lA = &lds[cb][0][0];
        const u16* lB = &lds[cb][1][0];

#pragma unroll
        for (int m = 0; m < 4; ++m) {
            const int ro = ((wr << 7) + (m << 4) + fr) * 64;
            Af[m][0] = *(const short8*)&lA[ro + kc0];
            Af[m][1] = *(const short8*)&lA[ro + kc1];
        }
#pragma unroll
        for (int n = 0; n < 2; ++n) {
            const int ro = ((wc << 6) + (n << 4) + fr) * 64;
            Bf[n][0] = *(const short8*)&lB[ro + kc0];
            Bf[n][1] = *(const short8*)&lB[ro + kc1];
        }
        if (t + 1 < T) stage(t + 1, 1, 0, cb ^ 1);
        asm volatile("" ::: "memory");
        __builtin_amdgcn_s_barrier();
        asm volatile("s_waitcnt lgkmcnt(0)" ::: "memory");
        __builtin_amdgcn_sched_barrier(0);
        __builtin_amdgcn_s_setprio(1);
        quad(0, 0);
        __builtin_amdgcn_s_setprio(0);
        asm volatile("" ::: "memory");
        __builtin_amdgcn_s_barrier();

#pragma unroll
        for (int n = 2; n < 4; ++n) {
            const int ro = ((wc << 6) + (n << 4) + fr) * 64;
            Bf[n][0] = *(const short8*)&lB[ro + kc0];
            Bf[n][1] = *(const short8*)&lB[ro + kc1];
        }
        if (t + 2 < T) stage(t + 2, 0, 0, cb);
        asm volatile("" ::: "memory");
        __builtin_amdgcn_s_barrier();
        asm volatile("s_waitcnt lgkmcnt(0)" ::: "memory");
        __builtin_amdgcn_sched_barrier(0);
        __builtin_amdgcn_s_setprio(1);
        quad(0, 2);
        __builtin_amdgcn_s_setprio(0);
        asm volatile("" ::: "memory");
        __builtin_amdgcn_s_barrier();

#pragma unroll
        for (int m = 0; m < 4; ++m) {
            const int ro = ((wr << 7) + ((m + 4) << 4) + fr) * 64;
            Af[m][0] = *(const short8*)&lA[ro + kc0];
            Af[m][1] = *(const short8*)&lA[ro + kc1];
        }
        if (t + 2 < T) stage(t + 2, 1, 1, cb);
        asm volatile("" ::: "memory");
        __builtin_amdgcn_s_barrier();
        asm volatile("s_waitcnt lgkmcnt(0)" ::: "memory");
        __builtin_amdgcn_sched_barrier(0);
        __builtin_amdgcn_s_setprio(1);
        quad(4, 2);
        __builtin_amdgcn_s_setprio(0);
        asm volatile("" ::: "memory");
        __builtin_amdgcn_s_barrier();

        if (t + 2 < T) stage(t + 2, 0, 1, cb);
        asm volatile("" ::: "memory");
        __builtin_amdgcn_s_barrier();
        __builtin_amdgcn_s_setprio(1);
        quad(4, 0);
        __builtin_amdgcn_s_setprio(0);
        if (t + 1 < T) {
            if (t + 2 < T) asm volatile("s_waitcnt vmcnt(6)" ::: "memory");
            else           asm volatile("s_waitcnt vmcnt(0)" ::: "memory");
        }
        asm volatile("" ::: "memory");
        __builtin_amdgcn_s_barrier();
    }

    const int oid = (int)(tileN >> 10);
    __syncthreads();
    if (oid < 2) {
        u16* l2 = (u16*)&lds[0][0][0];
#pragma unroll
        for (int j = 0; j < 4; ++j) {
            const int col = (wc << 6) + (j << 4) + fr;
            const int c   = col >> 3;
            const float bv = bcat[tileN + col];
#pragma unroll
            for (int i = 0; i < 8; ++i) {
                const int row0 = (wr << 7) + (i << 4) + (fq << 2);
#pragma unroll
                for (int r = 0; r < 4; ++r) {
                    const int row = row0 + r;
                    l2[row * 256 + (((c + row) & 31) << 3) + (col & 7)] = f2bf(acc[i][j][r] + bv);
                }
            }
        }
        __syncthreads();
        u16* P = oid ? Pk : Pq;
        const long colN = tileN & 1023;
#pragma unroll
        for (int it = 0; it < 16; ++it) {
            const int row = it * 16 + (tid >> 5);
            const int ch  = tid & 31;
            const short8 v = *(const short8*)&l2[row * 256 + (((ch + row) & 31) << 3)];
            *(short8*)&P[(tileM + row) * (long)Dd + colN + ch * 8] = v;
        }
    } else {
        char* l2c = (char*)&lds[0][0][0];
#pragma unroll
        for (int j = 0; j < 4; ++j) {
            const int col = (wc << 6) + (j << 4) + fr;
            const float bv = bcat[tileN + col];
            const int swz = (col & 7) << 4;
#pragma unroll
            for (int i = 0; i < 8; ++i) {
                const int row0 = (wr << 7) + (i << 4) + (fq << 2);
                const u64 pk = (u64)f2bf(acc[i][j][0] + bv)
                             | ((u64)f2bf(acc[i][j][1] + bv) << 16)
                             | ((u64)f2bf(acc[i][j][2] + bv) << 32)
                             | ((u64)f2bf(acc[i][j][3] + bv) << 48);
                *(u64*)(l2c + col * 512 + ((row0 * 2) ^ swz)) = pk;
            }
        }
        __syncthreads();
        const long b  = tileM >> 10, tm = tileM & 1023;
        const long colN = tileN & 1023;
#pragma unroll
        for (int it = 0; it < 16; ++it) {
            const int col = it * 16 + (tid >> 5);
            const int ch  = tid & 31;
            const short8 v = *(const short8*)(l2c + col * 512 + ((ch * 16) ^ ((col & 7) << 4)));
            *(short8*)&Pv[b * sMDc + (colN + col) * (long)Mm + tm + ch * 8] = v;
        }
    }
}

// ---------------- fused fp32->bf16 conversion + column-mean pooling ----------------
__global__ __launch_bounds__(256) void conv_pool(
    const float* __restrict__ oV, const float* __restrict__ oT,
    u16* __restrict__ oVb, u16* __restrict__ oTb,
    float* __restrict__ vpool, float* __restrict__ tpool)
{
    const int b = blockIdx.y, srci = blockIdx.z;
    const float* src = (srci ? oT : oV) + (size_t)b * Mm * Dd;
    u16* dst = (srci ? oTb : oVb) + (size_t)b * Mm * Dd;
    const int c4 = threadIdx.x * 4;
    const int r0 = blockIdx.x * 64;
    float4 s = {0.f, 0.f, 0.f, 0.f};
    for (int r = r0; r < r0 + 64; ++r) {
        const float4 v = *(const float4*)&src[(size_t)r * Dd + c4];
        s.x += v.x; s.y += v.y; s.z += v.z; s.w += v.w;
        ushort4 o;
        o.x = f2bf(v.x); o.y = f2bf(v.y); o.z = f2bf(v.z); o.w = f2bf(v.w);
        *(ushort4*)&dst[(size_t)r * Dd + c4] = o;
    }
    float* pool = (srci ? tpool : vpool) + (size_t)b * Dd + c4;
    atomicAdd(pool + 0, s.x * (1.0f / Mm));
    atomicAdd(pool + 1, s.y * (1.0f / Mm));
    atomicAdd(pool + 2, s.z * (1.0f / Mm));
    atomicAdd(pool + 3, s.w * (1.0f / Mm));
}

// ---------------- 6x weight fp32 -> bf16 ----------------
__global__ __launch_bounds__(256) void wconv6(
    const float* __restrict__ w0, const float* __restrict__ w1, const float* __restrict__ w2,
    const float* __restrict__ w3, const float* __restrict__ w4, const float* __restrict__ w5,
    u16* __restrict__ dst)
{
    const float* src;
    switch (blockIdx.y) {
        case 0: src = w0; break; case 1: src = w1; break; case 2: src = w2; break;
        case 3: src = w3; break; case 4: src = w4; break; default: src = w5; break;
    }
    const size_t i = (size_t)blockIdx.x * 256 + threadIdx.x;
    const float4 a = ((const float4*)src)[2 * i];
    const float4 b = ((const float4*)src)[2 * i + 1];
    short8 o;
    o[0]=(short)f2bf(a.x); o[1]=(short)f2bf(a.y); o[2]=(short)f2bf(a.z); o[3]=(short)f2bf(a.w);
    o[4]=(short)f2bf(b.x); o[5]=(short)f2bf(b.y); o[6]=(short)f2bf(b.z); o[7]=(short)f2bf(b.w);
    *(short8*)(dst + (((size_t)blockIdx.y) << 20) + 8 * i) = o;
}

// ---------------- concat 6 bias vectors ----------------
__global__ __launch_bounds__(256) void bcat_kernel(
    const float* __restrict__ b0, const float* __restrict__ b1, const float* __restrict__ b2,
    const float* __restrict__ b3, const float* __restrict__ b4, const float* __restrict__ b5,
    float* __restrict__ out)
{
    const int i = blockIdx.x * 256 + threadIdx.x;
    const int seg = i >> 10;
    const float* s;
    switch (seg) {
        case 0: s = b0; break; case 1: s = b1; break; case 2: s = b2; break;
        case 3: s = b3; break; case 4: s = b4; break; default: s = b5; break;
    }
    out[i] = s[i & 1023];
}

// ---------------- FFN ----------------
__global__ __launch_bounds__(256) void ffn1_kernel(
    const float* __restrict__ vpool, const float* __restrict__ tpool,
    const float* __restrict__ f1w, const float* __restrict__ f1b,
    float* __restrict__ hbuf)
{
    const int j = blockIdx.x, b = blockIdx.y;
    const int t = threadIdx.x, wv = t >> 6, lane = t & 63;
    __shared__ float red[4];
    const float* w = f1w + (size_t)j * (2 * Dd);
    float a = 0.f;
    for (int k = t; k < Dd; k += 256) a += vpool[b * Dd + k] * w[k];
    for (int k = t; k < Dd; k += 256) a += tpool[b * Dd + k] * w[Dd + k];
    a = waveSum(a);
    if (lane == 0) red[wv] = a;
    __syncthreads();
    if (t == 0) hbuf[b * HIDh + j] = fmaxf(red[0] + red[1] + red[2] + red[3] + f1b[j], 0.0f);
}

__global__ __launch_bounds__(256) void ffn2_kernel(
    const float* __restrict__ hbuf, const float* __restrict__ f2w,
    const float* __restrict__ f2b, float* __restrict__ lbuf)
{
    const int b = blockIdx.x;
    const int t = threadIdx.x, wv = t >> 6, lane = t & 63;
    __shared__ float red[4];
    float p = 0.f;
    for (int j = t; j < HIDh; j += 256) p += hbuf[b * HIDh + j] * f2w[j];
    p = waveSum(p);
    if (lane == 0) red[wv] = p;
    __syncthreads();
    if (t == 0) {
        const float z = red[0] + red[1] + red[2] + red[3] + f2b[0];
        lbuf[b] = 1.0f / (1.0f + expf(-z));
    }
}

// ---------------- sim softmax -> fp32 mask (d_out) + u8 row-major mask ----------------
__global__ __launch_bounds__(256) void sim_softmax_mask(
    const u16* __restrict__ scores, const float* __restrict__ lbuf,
    float* __restrict__ maskF, u8* __restrict__ maskR)
{
    const int row = blockIdx.x, b = blockIdx.y;
    const int t = threadIdx.x, wv = t >> 6, lane = t & 63;
    __shared__ float red[8];
    const size_t off = ((size_t)b * Mm + row) * Nn;
    const uint2 sv = *(const uint2*)(scores + off + 4 * t);
    const float x0 = bf2f((u16)(sv.x & 0xFFFFu)) * INV_SQRT_D;
    const float x1 = bf2f((u16)(sv.x >> 16))     * INV_SQRT_D;
    const float x2 = bf2f((u16)(sv.y & 0xFFFFu)) * INV_SQRT_D;
    const float x3 = bf2f((u16)(sv.y >> 16))     * INV_SQRT_D;
    float mx = waveMax(fmaxf(fmaxf(x0, x1), fmaxf(x2, x3)));
    if (lane == 0) red[wv] = mx;
    __syncthreads();
    mx = fmaxf(fmaxf(red[0], red[1]), fmaxf(red[2], red[3]));
    const float e0 = expf(x0 - mx), e1 = expf(x1 - mx), e2 = expf(x2 - mx), e3 = expf(x3 - mx);
    float s = waveSum(e0 + e1 + e2 + e3);
    if (lane == 0) red[4 + wv] = s;
    __syncthreads();
    const float inv = 1.0f / fmaxf(red[4] + red[5] + red[6] + red[7], 1e-30f);
    const float l = lbuf[b];
    float4 mk;
    mk.x = (e0 * inv >= l) ? 1.0f : 0.0f;
    mk.y = (e1 * inv >= l) ? 1.0f : 0.0f;
    mk.z = (e2 * inv >= l) ? 1.0f : 0.0f;
    mk.w = (e3 * inv >= l) ? 1.0f : 0.0f;
    *(float4*)(maskF + off + 4 * t) = mk;
    const u32 u8mk = (mk.x != 0.f ? 1u : 0u) | (mk.y != 0.f ? 0x100u : 0u)
                   | (mk.z != 0.f ? 0x10000u : 0u) | (mk.w != 0.f ? 0x1000000u : 0u);
    *(u32*)(maskR + off + 4 * t) = u8mk;
}

// ---------------- mask transpose: u8 maskR[b][m][n] -> u8 maskT[b][n][m] ----------------
__global__ __launch_bounds__(256) void transpose_mask(
    const u8* __restrict__ maskR, u8* __restrict__ maskT)
{
    __shared__ u8 tile[64][68];
    const int m0 = blockIdx.x * 64, n0 = blockIdx.y * 64, b = blockIdx.z;
    const int t = threadIdx.x;
    const int r = t >> 2, c = (t & 3) * 16;
    const uint4 src = *(const uint4*)(maskR + ((size_t)b * Mm + (m0 + r)) * Nn + n0 + c);
    *(uint4*)&tile[r][c] = src;
    __syncthreads();
    union { u8 b[16]; uint4 v; } pk;
#pragma unroll
    for (int k = 0; k < 16; ++k) pk.b[k] = tile[c + k][r];
    *(uint4*)(maskT + ((size_t)b * Nn + (n0 + r)) * Mm + m0 + c) = pk.v;
}

// ---------------- merged masked softmax (both branches), IN-PLACE bf16 ----------------
__global__ __launch_bounds__(256) void masked_softmax2(
    u16* __restrict__ Sa, u16* __restrict__ Sb,
    const u8* __restrict__ mR, const u8* __restrict__ mT)
{
    const int row = blockIdx.x, bb = blockIdx.y;
    const int br = bb >> 4, b = bb & 15;
    u16* scores = br ? Sb : Sa;
    const u8* mask = br ? mT : mR;
    const int t = threadIdx.x, wv = t >> 6, lane = t & 63;
    __shared__ float red[8];
    const size_t off = ((size_t)b * Mm + row) * Nn;
    const uint2 sv = *(const uint2*)(scores + off + 4 * t);
    float x0 = bf2f((u16)(sv.x & 0xFFFFu)) * INV_SQRT_D;
    float x1 = bf2f((u16)(sv.x >> 16))     * INV_SQRT_D;
    float x2 = bf2f((u16)(sv.y & 0xFFFFu)) * INV_SQRT_D;
    float x3 = bf2f((u16)(sv.y >> 16))     * INV_SQRT_D;
    const u32 mk = *(const u32*)(mask + off + 4 * t);
    if (!(mk & 0x000000FFu)) x0 = NEGINF;
    if (!(mk & 0x0000FF00u)) x1 = NEGINF;
    if (!(mk & 0x00FF0000u)) x2 = NEGINF;
    if (!(mk & 0xFF000000u)) x3 = NEGINF;
    float mx = waveMax(fmaxf(fmaxf(x0, x1), fmaxf(x2, x3)));
    if (lane == 0) red[wv] = mx;
    __syncthreads();
    mx = fmaxf(fmaxf(red[0], red[1]), fmaxf(red[2], red[3]));
    const float e0 = expf(x0 - mx), e1 = expf(x1 - mx), e2 = expf(x2 - mx), e3 = expf(x3 - mx);
    float s = waveSum(e0 + e1 + e2 + e3);
    if (lane == 0) red[4 + wv] = s;
    __syncthreads();
    const float inv = 1.0f / fmaxf(red[4] + red[5] + red[6] + red[7], 1e-30f);
    uint2 pk;
    pk.x = (u32)f2bf(e0 * inv) | ((u32)f2bf(e1 * inv) << 16);
    pk.y = (u32)f2bf(e2 * inv) | ((u32)f2bf(e3 * inv) << 16);
    *(uint2*)(scores + off + 4 * t) = pk;
}

extern "C" void kernel_launch(void* const* d_in, const int* in_sizes, int n_in,
                              void* d_out, int out_size, void* d_ws, size_t ws_size,
                              hipStream_t stream)
{
    (void)in_sizes; (void)n_in; (void)out_size; (void)ws_size;
    const float* oV     = (const float*)d_in[0];
    const float* oT     = (const float*)d_in[1];
    const float* Wq_v_w = (const float*)d_in[2];
    const float* Wq_v_b = (const float*)d_in[3];
    const float* Wk_t_w = (const float*)d_in[4];
    const float* Wk_t_b = (const float*)d_in[5];
    const float* Wv_t_w = (const float*)d_in[6];
    const float* Wv_t_b = (const float*)d_in[7];
    const float* Wq_t_w = (const float*)d_in[8];
    const float* Wq_t_b = (const float*)d_in[9];
    const float* Wk_v_w = (const float*)d_in[10];
    const float* Wk_v_b = (const float*)d_in[11];
    const float* Wv_v_w = (const float*)d_in[12];
    const float* Wv_v_b = (const float*)d_in[13];
    const float* f1w    = (const float*)d_in[14];
    const float* f1b    = (const float*)d_in[15];
    const float* f2w    = (const float*)d_in[16];
    const float* f2b    = (const float*)d_in[17];

    float* out_vt = (float*)d_out;
    float* out_tv = out_vt + BMDc;
    float* maskF  = out_vt + 2 * BMDc;

    // workspace layout (~365 MB of 768 MB)
    u16* S0a = (u16*)d_ws;                       // Qv
    u16* S1a = S0a + BMDc;                       // Kt
    u16* S2a = S1a + BMDc;                       // Vt^T
    u16* S0b = S2a + BMDc;                       // Qt
    u16* S1b = S0b + BMDc;                       // Kv
    u16* S2b = S1b + BMDc;                       // Vv^T
    u16* S3a = S2b + BMDc;                       // scores/attn V->T
    u16* S3b = S3a + BMDc;                       // scores/attn T->V
    u16* oVb = S3b + BMDc;
    u16* oTb = oVb + BMDc;
    u16* Wc  = oTb + BMDc;                       // 6x bf16 weights
    u8*  maskT = (u8*)(Wc + 6 * (1 << 20));
    u8*  maskR = maskT + BMDc;
    float* bcat  = (float*)(maskR + BMDc);
    float* vpool = bcat + 6144;
    float* tpool = vpool + Bz * Dd;
    float* hbuf  = tpool + Bz * Dd;
    float* lbuf  = hbuf + Bz * HIDh;

    const dim3 blk(256), blk512(512);
    const dim3 gBat(Mm / 256, Nn / 256, Bz);            // 256 wg
    const dim3 gBat2(Mm / 256, Nn / 256, 2 * Bz);       // 512 wg (merged branches)
    const dim3 gFproj(64, 12, 2);                       // 1536 wg (merged inputs)
    const dim3 gRow2(Mm, 2 * Bz);
    const dim3 gTrp(Mm / 64, Nn / 64, Bz);
    const long sMD = sMDc, sMN = (long)Mm * Nn;

    // 0: weights + biases to bf16/concat
    wconv6<<<dim3(512, 6), blk, 0, stream>>>(Wq_v_w, Wk_v_w, Wv_v_w, Wq_t_w, Wk_t_w, Wv_t_w, Wc);
    bcat_kernel<<<dim3(24), blk, 0, stream>>>(Wq_v_b, Wk_v_b, Wv_v_b, Wq_t_b, Wk_t_b, Wv_t_b, bcat);

    // 1: fused convert + pool -> FFN threshold
    hipMemsetAsync(vpool, 0, 2 * Bz * Dd * sizeof(float), stream);
    conv_pool<<<dim3(16, Bz, 2), blk, 0, stream>>>(oV, oT, oVb, oTb, vpool, tpool);
    ffn1_kernel<<<dim3(HIDh, Bz), blk, 0, stream>>>(vpool, tpool, f1w, f1b, hbuf);
    ffn2_kernel<<<dim3(Bz), blk, 0, stream>>>(hbuf, f2w, f2b, lbuf);

    // 2: sim scores -> masks
    gemm256<false><<<gBat, blk512, 0, stream>>>(oVb, oTb, S3a, oVb, oTb, S3a, Dd, Nn, sMD, sMD, sMN);
    sim_softmax_mask<<<dim3(Mm, Bz), blk, 0, stream>>>(S3a, lbuf, maskF, maskR);
    transpose_mask<<<gTrp, blk, 0, stream>>>(maskR, maskT);

    // 3: merged projections (both inputs, one dispatch)
    gemm_proj3<<<gFproj, blk512, 0, stream>>>(oVb, oTb, Wc, bcat,
                                              S0a, S1b, S2b, S0b, S1a, S2a, Dd);

    // 4: merged score GEMM (V->T and T->V)
    gemm256<false><<<gBat2, blk512, 0, stream>>>(S0a, S1a, S3a, S0b, S1b, S3b, Dd, Nn, sMD, sMD, sMN);

    // 5: merged masked softmax
    masked_softmax2<<<gRow2, blk, 0, stream>>>(S3a, S3b, maskR, maskT);

    // 6: merged PV GEMM
    gemm256<true><<<gBat2, blk512, 0, stream>>>(S3a, S2a, out_vt, S3b, S2b, out_tv, Nn, Dd, sMN, sMD, sMD);
}